// Round 1
// baseline (818.004 us; speedup 1.0000x reference)
//
#include <hip/hip_runtime.h>

typedef _Float16 f16;
typedef _Float16 half8 __attribute__((ext_vector_type(8)));
typedef float floatx4 __attribute__((ext_vector_type(4)));

#define L_TOT   3072
#define L_NZ    2048
#define DIM_C   2048
#define NH      16
#define HD      128

// ---------------------------------------------------------------- helpers
__device__ __forceinline__ void gl_lds16(const f16* g, f16* l) {
    // async global->LDS, 16B per lane; LDS dest = wave-uniform base + lane*16
    __builtin_amdgcn_global_load_lds((__attribute__((address_space(1))) void*)g,
                                     (__attribute__((address_space(3))) void*)l,
                                     16, 0, 0);
}

__global__ void sentinel_kernel(float* out) { out[0] = 1.0e6f; }

// ---------------------------------------------------------------- cast f32 -> f16
__global__ __launch_bounds__(256)
void cast_f32_f16(const float* __restrict__ in, f16* __restrict__ out, int n) {
    int i = (blockIdx.x * 256 + threadIdx.x) * 4;
    if (i + 3 < n) {
        float4 v = *(const float4*)(in + i);
        out[i+0] = (f16)v.x; out[i+1] = (f16)v.y;
        out[i+2] = (f16)v.z; out[i+3] = (f16)v.w;
    }
}

// ---------------------------------------------------------------- transpose (+cast) -> f16, out[c][r] = in[r][c]
template<typename TIN>
__global__ __launch_bounds__(256)
void transpose_cast(const TIN* __restrict__ in, f16* __restrict__ out,
                    int R, int C, long long inBatch, long long outBatch) {
    in  += (long long)blockIdx.z * inBatch;
    out += (long long)blockIdx.z * outBatch;
    __shared__ f16 tile[32][33];
    int x = threadIdx.x & 31, y0 = threadIdx.x >> 5;
    int r0 = blockIdx.y * 32, c0 = blockIdx.x * 32;
#pragma unroll
    for (int i = 0; i < 4; ++i) {
        int y = y0 + i * 8;
        tile[y][x] = (f16)(float)in[(size_t)(r0 + y) * C + (c0 + x)];
    }
    __syncthreads();
#pragma unroll
    for (int i = 0; i < 4; ++i) {
        int y = y0 + i * 8;
        out[(size_t)(c0 + y) * R + (r0 + x)] = tile[x][y];
    }
}

// ---------------------------------------------------------------- GEMM C[M][N] = A[M][K] * BT[N][K]^T  (f16 in, f32 acc)
// 128x128 tile, BK=32, 4 waves (2x2), each wave 64x64 via 4x4 16x16x32 MFMA frags.
template<int WRITE_HALF, int ACCUM, int ADD_BIAS>
__global__ __launch_bounds__(256)
void gemm_tn(const f16* __restrict__ A, const f16* __restrict__ BT,
             void* __restrict__ Cv, const float* __restrict__ bias,
             int M, int N, int K, int lda, int ldb, int ldc, float cscale) {
    __shared__ __align__(16) f16 lds_a[128 * 32];
    __shared__ __align__(16) f16 lds_b[128 * 32];
    const int tid  = threadIdx.x;
    const int lane = tid & 63, wave = tid >> 6;
    const int m0 = blockIdx.y * 128, n0 = blockIdx.x * 128;
    const int wr = wave >> 1, wc = wave & 1;
    floatx4 acc[4][4] = {};

    // staging: per wave 2 issues of 64 lanes * 8 f16 each, for A and B tiles
    int e0 = ((wave * 2 + 0) * 64 + lane) * 8;
    int e1 = ((wave * 2 + 1) * 64 + lane) * 8;
    int row0 = e0 >> 5, kk0 = e0 & 31;
    int row1 = e1 >> 5, kk1 = e1 & 31;
    const f16* gA0 = A  + (size_t)(m0 + row0) * lda + kk0;
    const f16* gA1 = A  + (size_t)(m0 + row1) * lda + kk1;
    const f16* gB0 = BT + (size_t)(n0 + row0) * ldb + kk0;
    const f16* gB1 = BT + (size_t)(n0 + row1) * ldb + kk1;
    f16* la0 = lds_a + (wave * 2 + 0) * 512;
    f16* la1 = lds_a + (wave * 2 + 1) * 512;
    f16* lb0 = lds_b + (wave * 2 + 0) * 512;
    f16* lb1 = lds_b + (wave * 2 + 1) * 512;

    const int rl = lane & 15, kq = (lane >> 4) * 8;

    for (int k0 = 0; k0 < K; k0 += 32) {
        if (k0) __syncthreads();
        gl_lds16(gA0, la0); gl_lds16(gA1, la1);
        gl_lds16(gB0, lb0); gl_lds16(gB1, lb1);
        gA0 += 32; gA1 += 32; gB0 += 32; gB1 += 32;
        __syncthreads();   // drains vmcnt -> staged data visible
        half8 af[4], bf[4];
#pragma unroll
        for (int m = 0; m < 4; ++m)
            af[m] = *(const half8*)(lds_a + (wr * 64 + m * 16 + rl) * 32 + kq);
#pragma unroll
        for (int n = 0; n < 4; ++n)
            bf[n] = *(const half8*)(lds_b + (wc * 64 + n * 16 + rl) * 32 + kq);
#pragma unroll
        for (int m = 0; m < 4; ++m)
#pragma unroll
            for (int n = 0; n < 4; ++n)
                acc[m][n] = __builtin_amdgcn_mfma_f32_16x16x32_f16(af[m], bf[n], acc[m][n], 0, 0, 0);
    }

    // epilogue: C col = lane&15, row = (lane>>4)*4 + j   (verified layout)
    const int rq = lane >> 4;
#pragma unroll
    for (int m = 0; m < 4; ++m) {
        int row = m0 + wr * 64 + m * 16 + rq * 4;
#pragma unroll
        for (int n = 0; n < 4; ++n) {
            int col = n0 + wc * 64 + n * 16 + rl;
            float badd = ADD_BIAS ? bias[col] : 0.0f;
#pragma unroll
            for (int j = 0; j < 4; ++j) {
                float v = acc[m][n][j] * cscale + badd;
                size_t idx = (size_t)(row + j) * ldc + col;
                if (WRITE_HALF) {
                    f16* C = (f16*)Cv;
                    if (ACCUM) v += (float)C[idx];
                    C[idx] = (f16)v;
                } else {
                    float* C = (float*)Cv;
                    if (ACCUM) v += C[idx];
                    C[idx] = v;
                }
            }
        }
    }
}

// ---------------------------------------------------------------- RMS norm + RoPE, writes head-major q/k (q pre-scaled 1/sqrt(128)) and v
__global__ __launch_bounds__(128)
void norm_rope_kernel(const f16* __restrict__ q16, const f16* __restrict__ k16, const f16* __restrict__ v16,
                      const float* __restrict__ qs, const float* __restrict__ ks, const float* __restrict__ vs,
                      const float* __restrict__ nrope, const float* __restrict__ crope,
                      f16* __restrict__ qH, f16* __restrict__ kH, f16* __restrict__ vH) {
    const int r = blockIdx.x, h = blockIdx.y, d = threadIdx.x;
    const size_t src = (size_t)r * DIM_C + h * HD + d;
    float qv = (float)q16[src], kv = (float)k16[src], vv = (float)v16[src];
    float sq = qv * qv, sk = kv * kv, sv = vv * vv;
#pragma unroll
    for (int m = 1; m < 64; m <<= 1) {
        sq += __shfl_xor(sq, m);
        sk += __shfl_xor(sk, m);
        sv += __shfl_xor(sv, m);
    }
    __shared__ float part[3][2];
    const int wid = d >> 6;
    if ((d & 63) == 0) { part[0][wid] = sq; part[1][wid] = sk; part[2][wid] = sv; }
    __syncthreads();
    float rq = rsqrtf((part[0][0] + part[0][1]) * (1.0f / 128.0f) + 1e-6f);
    float rk = rsqrtf((part[1][0] + part[1][1]) * (1.0f / 128.0f) + 1e-6f);
    float rv = rsqrtf((part[2][0] + part[2][1]) * (1.0f / 128.0f) + 1e-6f);
    float qn = qv * rq * qs[d];
    float kn = kv * rk * ks[d];
    float vn = vv * rv * vs[d];
    __shared__ float shq[128], shk[128];
    shq[d] = qn; shk[d] = kn;
    __syncthreads();
    float rotq = (d < 64) ? -shq[d + 64] : shq[d - 64];
    float rotk = (d < 64) ? -shk[d + 64] : shk[d - 64];
    const float* rp = (r < L_NZ) ? (nrope + (size_t)r * HD) : (crope + (size_t)(r - L_NZ) * HD);
    float fr = rp[d];
    float c = cosf(fr), s = sinf(fr);
    const size_t dst = ((size_t)h * L_TOT + r) * HD + d;
    qH[dst] = (f16)((qn * c + rotq * s) * 0.08838834764831845f);  // 1/sqrt(128)
    kH[dst] = (f16)(kn * c + rotk * s);
    vH[dst] = (f16)vn;
}

// ---------------------------------------------------------------- flash attention
// grid (48 qblocks, 16 heads), 256 thr = 4 waves, wave = 16 queries, 32-key chunks.
__global__ __launch_bounds__(256)
void flash_kernel(const f16* __restrict__ qH, const f16* __restrict__ kH,
                  const f16* __restrict__ vT, f16* __restrict__ xH) {
    __shared__ __align__(16) f16 p_lds[4][16][40];
    const int tid = threadIdx.x;
    const int lane = tid & 63, w = tid >> 6;
    const int h = blockIdx.y;
    const int q0 = blockIdx.x * 64 + w * 16;
    const int rl = lane & 15, rq = lane >> 4;

    const f16* qbase = qH + ((size_t)h * L_TOT + q0 + rl) * HD;
    half8 af[4];
#pragma unroll
    for (int kc = 0; kc < 4; ++kc)
        af[kc] = *(const half8*)(qbase + kc * 32 + rq * 8);

    floatx4 acc[8] = {};
    float m_run[4] = {-1e30f, -1e30f, -1e30f, -1e30f};
    float l_run[4] = {0.f, 0.f, 0.f, 0.f};

    const int kLo = (q0 >= L_NZ) ? L_NZ : 0;   // cond queries attend only cond keys
    const f16* khead = kH + (size_t)h * L_TOT * HD;
    const f16* vhead = vT + (size_t)h * HD * L_TOT;

    for (int kb = kLo; kb < L_TOT; kb += 32) {
        floatx4 sacc[2];
#pragma unroll
        for (int g = 0; g < 2; ++g) {
            floatx4 z = {0.f, 0.f, 0.f, 0.f};
            sacc[g] = z;
            const f16* kr = khead + (size_t)(kb + g * 16 + rl) * HD + rq * 8;
#pragma unroll
            for (int kc = 0; kc < 4; ++kc)
                sacc[g] = __builtin_amdgcn_mfma_f32_16x16x32_f16(af[kc], *(const half8*)(kr + kc * 32), sacc[g], 0, 0, 0);
        }
        // online softmax across the 32 keys (scores: row=(rq*4+j), col-key=(g*16+rl))
#pragma unroll
        for (int j = 0; j < 4; ++j) {
            float bm = fmaxf(sacc[0][j], sacc[1][j]);
#pragma unroll
            for (int mm = 1; mm < 16; mm <<= 1) bm = fmaxf(bm, __shfl_xor(bm, mm));
            float mn = fmaxf(m_run[j], bm);
            float sc = __expf(m_run[j] - mn);
            m_run[j] = mn;
            float p0 = __expf(sacc[0][j] - mn);
            float p1 = __expf(sacc[1][j] - mn);
            float ps = p0 + p1;
#pragma unroll
            for (int mm = 1; mm < 16; mm <<= 1) ps += __shfl_xor(ps, mm);
            l_run[j] = l_run[j] * sc + ps;
#pragma unroll
            for (int n = 0; n < 8; ++n) acc[n][j] *= sc;
            p_lds[w][rq * 4 + j][rl]      = (f16)p0;
            p_lds[w][rq * 4 + j][16 + rl] = (f16)p1;
        }
        // PV: A = P[16q][32k] (re-read in MFMA-A layout), B = V[32k][128d] from vT
        half8 ap = *(const half8*)(&p_lds[w][rl][rq * 8]);
        const f16* vb = vhead + kb + rq * 8;
#pragma unroll
        for (int n = 0; n < 8; ++n) {
            half8 bv = *(const half8*)(vb + (size_t)(n * 16 + rl) * L_TOT);
            acc[n] = __builtin_amdgcn_mfma_f32_16x16x32_f16(ap, bv, acc[n], 0, 0, 0);
        }
    }

    float li[4];
#pragma unroll
    for (int j = 0; j < 4; ++j) li[j] = 1.0f / l_run[j];
#pragma unroll
    for (int n = 0; n < 8; ++n)
#pragma unroll
        for (int j = 0; j < 4; ++j) {
            size_t dst = (size_t)(q0 + rq * 4 + j) * DIM_C + h * HD + n * 16 + rl;
            xH[dst] = (f16)(acc[n][j] * li[j]);
        }
}

// ---------------------------------------------------------------- launch
extern "C" void kernel_launch(void* const* d_in, const int* in_sizes, int n_in,
                              void* d_out, int out_size, void* d_ws, size_t ws_size,
                              hipStream_t stream) {
    const float* noise = (const float*)d_in[0];
    const float* cond  = (const float*)d_in[1];
    const float* nrope = (const float*)d_in[2];
    const float* crope = (const float*)d_in[3];
    const float* Wq = (const float*)d_in[4];
    const float* Wk = (const float*)d_in[5];
    const float* Wv = (const float*)d_in[6];
    const float* Wo = (const float*)d_in[7];
    const float* bq = (const float*)d_in[8];
    const float* bk = (const float*)d_in[9];
    const float* bv = (const float*)d_in[10];
    const float* bo = (const float*)d_in[11];
    const float* qs = (const float*)d_in[12];
    const float* ks = (const float*)d_in[13];
    const float* vs = (const float*)d_in[14];
    const float* lqd = (const float*)d_in[15];
    const float* lqu = (const float*)d_in[16];
    const float* lkd = (const float*)d_in[17];
    const float* lku = (const float*)d_in[18];
    const float* lvd = (const float*)d_in[19];
    const float* lvu = (const float*)d_in[20];
    const float* lod = (const float*)d_in[21];
    const float* lou = (const float*)d_in[22];
    (void)in_sizes; (void)n_in; (void)out_size;

    char* ws = (char*)d_ws;
    const size_t SZ_LD = (size_t)L_TOT * DIM_C * sizeof(f16);   // 12.58 MB
    const size_t SZ_W  = (size_t)DIM_C * DIM_C * sizeof(f16);   //  8.39 MB
    size_t o = 0;
    auto take = [&](size_t b) { size_t r = o; o += (b + 255) & ~(size_t)255; return r; };
    f16* jointH   = (f16*)(ws + take(SZ_LD));
    f16* WT0      = (f16*)(ws + take(SZ_W));
    f16* WT1      = (f16*)(ws + take(SZ_W));
    f16* WT2      = (f16*)(ws + take(SZ_W));
    f16* WT3      = (f16*)(ws + take(SZ_W));
    f16* downTqkv = (f16*)(ws + take((size_t)384 * 2048 * 2));
    f16* downTo   = (f16*)(ws + take((size_t)128 * 2048 * 2));
    f16* upT0     = (f16*)(ws + take((size_t)2048 * 128 * 2));
    f16* upT1     = (f16*)(ws + take((size_t)2048 * 128 * 2));
    f16* upT2     = (f16*)(ws + take((size_t)2048 * 128 * 2));
    f16* upTo     = (f16*)(ws + take((size_t)2048 * 128 * 2));
    f16* q16      = (f16*)(ws + take(SZ_LD));
    f16* k16      = (f16*)(ws + take(SZ_LD));
    f16* v16      = (f16*)(ws + take(SZ_LD));
    f16* t_all    = (f16*)(ws + take((size_t)1024 * 384 * 2));
    f16* t_o      = (f16*)(ws + take((size_t)1024 * 128 * 2));
    f16* qHd      = (f16*)(ws + take(SZ_LD));
    f16* kHd      = (f16*)(ws + take(SZ_LD));
    f16* vHd      = (f16*)(ws + take(SZ_LD));
    f16* vTd      = (f16*)(ws + take(SZ_LD));
    f16* xH       = (f16*)(ws + take(SZ_LD));
    if (o > ws_size) {  // workspace too small: emit sentinel so absmax ~1e6 flags it
        sentinel_kernel<<<1, 1, 0, stream>>>((float*)d_out);
        return;
    }

    // 1) casts + weight transposes (B^T layout, f16)
    cast_f32_f16<<<dim3((2048 * 2048) / 1024), 256, 0, stream>>>(noise, jointH, 2048 * 2048);
    cast_f32_f16<<<dim3((1024 * 2048) / 1024), 256, 0, stream>>>(cond, jointH + (size_t)2048 * 2048, 1024 * 2048);
    transpose_cast<float><<<dim3(64, 64, 1), 256, 0, stream>>>(Wq, WT0, 2048, 2048, 0, 0);
    transpose_cast<float><<<dim3(64, 64, 1), 256, 0, stream>>>(Wk, WT1, 2048, 2048, 0, 0);
    transpose_cast<float><<<dim3(64, 64, 1), 256, 0, stream>>>(Wv, WT2, 2048, 2048, 0, 0);
    transpose_cast<float><<<dim3(64, 64, 1), 256, 0, stream>>>(Wo, WT3, 2048, 2048, 0, 0);
    transpose_cast<float><<<dim3(4, 64, 1), 256, 0, stream>>>(lqd, downTqkv,                      2048, 128, 0, 0);
    transpose_cast<float><<<dim3(4, 64, 1), 256, 0, stream>>>(lkd, downTqkv + (size_t)128 * 2048, 2048, 128, 0, 0);
    transpose_cast<float><<<dim3(4, 64, 1), 256, 0, stream>>>(lvd, downTqkv + (size_t)256 * 2048, 2048, 128, 0, 0);
    transpose_cast<float><<<dim3(4, 64, 1), 256, 0, stream>>>(lod, downTo, 2048, 128, 0, 0);
    transpose_cast<float><<<dim3(64, 4, 1), 256, 0, stream>>>(lqu, upT0, 128, 2048, 0, 0);
    transpose_cast<float><<<dim3(64, 4, 1), 256, 0, stream>>>(lku, upT1, 128, 2048, 0, 0);
    transpose_cast<float><<<dim3(64, 4, 1), 256, 0, stream>>>(lvu, upT2, 128, 2048, 0, 0);
    transpose_cast<float><<<dim3(64, 4, 1), 256, 0, stream>>>(lou, upTo, 128, 2048, 0, 0);

    // 2) QKV projections (+bias) and LoRA (cond rows only)
    dim3 gqkv(2048 / 128, 3072 / 128);
    gemm_tn<1, 0, 1><<<gqkv, 256, 0, stream>>>(jointH, WT0, q16, bq, 3072, 2048, 2048, 2048, 2048, 2048, 1.0f);
    gemm_tn<1, 0, 1><<<gqkv, 256, 0, stream>>>(jointH, WT1, k16, bk, 3072, 2048, 2048, 2048, 2048, 2048, 1.0f);
    gemm_tn<1, 0, 1><<<gqkv, 256, 0, stream>>>(jointH, WT2, v16, bv, 3072, 2048, 2048, 2048, 2048, 2048, 1.0f);
    // stacked lora-down: t_all[1024][384] = joint_cond @ [Wdq|Wdk|Wdv]   (scale_lora = 128/128 = 1)
    gemm_tn<1, 0, 0><<<dim3(3, 8), 256, 0, stream>>>(jointH + (size_t)2048 * 2048, downTqkv, t_all, nullptr,
                                                     1024, 384, 2048, 2048, 2048, 384, 1.0f);
    dim3 gup(2048 / 128, 1024 / 128);
    gemm_tn<1, 1, 0><<<gup, 256, 0, stream>>>(t_all + 0,   upT0, q16 + (size_t)2048 * 2048, nullptr, 1024, 2048, 128, 384, 128, 2048, 1.0f);
    gemm_tn<1, 1, 0><<<gup, 256, 0, stream>>>(t_all + 128, upT1, k16 + (size_t)2048 * 2048, nullptr, 1024, 2048, 128, 384, 128, 2048, 1.0f);
    gemm_tn<1, 1, 0><<<gup, 256, 0, stream>>>(t_all + 256, upT2, v16 + (size_t)2048 * 2048, nullptr, 1024, 2048, 128, 384, 128, 2048, 1.0f);

    // 3) RMS norm + RoPE -> head-major; transpose v per head
    norm_rope_kernel<<<dim3(3072, 16), 128, 0, stream>>>(q16, k16, v16, qs, ks, vs, nrope, crope, qHd, kHd, vHd);
    transpose_cast<f16><<<dim3(4, 96, 16), 256, 0, stream>>>(vHd, vTd, 3072, 128,
                                                             (long long)3072 * 128, (long long)128 * 3072);

    // 4) flash attention -> xH [L][2048]
    flash_kernel<<<dim3(48, 16), 256, 0, stream>>>(qHd, kHd, vTd, xH);

    // 5) output projection (+bias) and LoRA-o
    gemm_tn<0, 0, 1><<<gqkv, 256, 0, stream>>>(xH, WT3, d_out, bo, 3072, 2048, 2048, 2048, 2048, 2048, 1.0f);
    gemm_tn<1, 0, 0><<<dim3(1, 8), 256, 0, stream>>>(xH + (size_t)2048 * 2048, downTo, t_o, nullptr,
                                                     1024, 128, 2048, 2048, 2048, 128, 1.0f);
    gemm_tn<0, 1, 0><<<gup, 256, 0, stream>>>(t_o, upTo, (float*)d_out + (size_t)2048 * 2048, nullptr,
                                              1024, 2048, 128, 128, 128, 2048, 1.0f);
}

// Round 4
// 560.693 us; speedup vs baseline: 1.4589x; 1.4589x over previous
//
#include <hip/hip_runtime.h>

typedef _Float16 f16;
typedef _Float16 half8 __attribute__((ext_vector_type(8)));
typedef float floatx4 __attribute__((ext_vector_type(4)));

#define L_TOT   3072
#define L_NZ    2048
#define DIM_C   2048
#define NH      16
#define HD      128

// ---------------------------------------------------------------- helpers
__device__ __forceinline__ void gl_lds16(const f16* g, f16* l) {
    // async global->LDS, 16B per lane; LDS dest = wave-uniform base + lane*16
    __builtin_amdgcn_global_load_lds((__attribute__((address_space(1))) void*)g,
                                     (__attribute__((address_space(3))) void*)l,
                                     16, 0, 0);
}

__global__ void sentinel_kernel(float* out) { out[0] = 1.0e6f; }

// ---------------------------------------------------------------- cast f32 -> f16
__global__ __launch_bounds__(256)
void cast_f32_f16(const float* __restrict__ in, f16* __restrict__ out, int n) {
    int i = (blockIdx.x * 256 + threadIdx.x) * 4;
    if (i + 3 < n) {
        float4 v = *(const float4*)(in + i);
        out[i+0] = (f16)v.x; out[i+1] = (f16)v.y;
        out[i+2] = (f16)v.z; out[i+3] = (f16)v.w;
    }
}

// ---------------------------------------------------------------- transpose (+cast) -> f16, out[c][r] = in[r][c]
template<typename TIN>
__global__ __launch_bounds__(256)
void transpose_cast(const TIN* __restrict__ in, f16* __restrict__ out,
                    int R, int C, long long inBatch, long long outBatch) {
    in  += (long long)blockIdx.z * inBatch;
    out += (long long)blockIdx.z * outBatch;
    __shared__ f16 tile[32][33];
    int x = threadIdx.x & 31, y0 = threadIdx.x >> 5;
    int r0 = blockIdx.y * 32, c0 = blockIdx.x * 32;
#pragma unroll
    for (int i = 0; i < 4; ++i) {
        int y = y0 + i * 8;
        tile[y][x] = (f16)(float)in[(size_t)(r0 + y) * C + (c0 + x)];
    }
    __syncthreads();
#pragma unroll
    for (int i = 0; i < 4; ++i) {
        int y = y0 + i * 8;
        out[(size_t)(c0 + y) * R + (r0 + x)] = tile[x][y];
    }
}

// ---------------------------------------------------------------- GEMM C[M][N] = A[M][K] * BT[N][K]^T  (f16 in, f32 acc)
// 128x128 tile, BK=32, 4 waves (2x2), each wave 64x64 via 4x4 16x16x32 MFMA frags.
// SPLIT3: N spans 3 chunks of 2048; chunk c writes to Cbase + c*3072*2048 with bias{0,1,2}.
template<int WRITE_HALF, int ACCUM, int ADD_BIAS, int SPLIT3>
__global__ __launch_bounds__(256)
void gemm_tn(const f16* __restrict__ A, const f16* __restrict__ BT,
             void* __restrict__ Cv,
             const float* __restrict__ bias0, const float* __restrict__ bias1,
             const float* __restrict__ bias2,
             int M, int N, int K, int lda, int ldb, int ldc, float cscale) {
    __shared__ __align__(16) f16 lds_a[128 * 32];
    __shared__ __align__(16) f16 lds_b[128 * 32];
    const int tid  = threadIdx.x;
    const int lane = tid & 63, wave = tid >> 6;
    const int m0 = blockIdx.y * 128, n0 = blockIdx.x * 128;
    const int wr = wave >> 1, wc = wave & 1;
    floatx4 acc[4][4] = {};

    int e0 = ((wave * 2 + 0) * 64 + lane) * 8;
    int e1 = ((wave * 2 + 1) * 64 + lane) * 8;
    int row0 = e0 >> 5, kk0 = e0 & 31;
    int row1 = e1 >> 5, kk1 = e1 & 31;
    const f16* gA0 = A  + (size_t)(m0 + row0) * lda + kk0;
    const f16* gA1 = A  + (size_t)(m0 + row1) * lda + kk1;
    const f16* gB0 = BT + (size_t)(n0 + row0) * ldb + kk0;
    const f16* gB1 = BT + (size_t)(n0 + row1) * ldb + kk1;
    f16* la0 = lds_a + (wave * 2 + 0) * 512;
    f16* la1 = lds_a + (wave * 2 + 1) * 512;
    f16* lb0 = lds_b + (wave * 2 + 0) * 512;
    f16* lb1 = lds_b + (wave * 2 + 1) * 512;

    const int rl = lane & 15, kq = (lane >> 4) * 8;

    for (int k0 = 0; k0 < K; k0 += 32) {
        if (k0) __syncthreads();
        gl_lds16(gA0, la0); gl_lds16(gA1, la1);
        gl_lds16(gB0, lb0); gl_lds16(gB1, lb1);
        gA0 += 32; gA1 += 32; gB0 += 32; gB1 += 32;
        __syncthreads();
        half8 af[4], bf[4];
#pragma unroll
        for (int m = 0; m < 4; ++m)
            af[m] = *(const half8*)(lds_a + (wr * 64 + m * 16 + rl) * 32 + kq);
#pragma unroll
        for (int n = 0; n < 4; ++n)
            bf[n] = *(const half8*)(lds_b + (wc * 64 + n * 16 + rl) * 32 + kq);
#pragma unroll
        for (int m = 0; m < 4; ++m)
#pragma unroll
            for (int n = 0; n < 4; ++n)
                acc[m][n] = __builtin_amdgcn_mfma_f32_16x16x32_f16(af[m], bf[n], acc[m][n], 0, 0, 0);
    }

    // epilogue: C col = lane&15, row = (lane>>4)*4 + j
    const int rq = lane >> 4;
    const float* bias = bias0;
    size_t cbase = 0;
    if (SPLIT3) {
        int chunk = n0 >> 11;
        bias = (chunk == 0) ? bias0 : ((chunk == 1) ? bias1 : bias2);
        cbase = (size_t)chunk * ((size_t)L_TOT * DIM_C);
    }
#pragma unroll
    for (int m = 0; m < 4; ++m) {
        int row = m0 + wr * 64 + m * 16 + rq * 4;
#pragma unroll
        for (int n = 0; n < 4; ++n) {
            int col = n0 + wc * 64 + n * 16 + rl;
            float badd = ADD_BIAS ? bias[SPLIT3 ? (col & 2047) : col] : 0.0f;
            int ccol = SPLIT3 ? (col & 2047) : col;
#pragma unroll
            for (int j = 0; j < 4; ++j) {
                float v = acc[m][n][j] * cscale + badd;
                size_t idx = cbase + (size_t)(row + j) * ldc + ccol;
                if (WRITE_HALF) {
                    f16* C = (f16*)Cv;
                    if (ACCUM) v += (float)C[idx];
                    C[idx] = (f16)v;
                } else {
                    float* C = (float*)Cv;
                    if (ACCUM) v += C[idx];
                    C[idx] = v;
                }
            }
        }
    }
}

// ---------------------------------------------------------------- RMS norm + RoPE, writes head-major q/k (q pre-scaled 1/sqrt(128)) and v
__global__ __launch_bounds__(128)
void norm_rope_kernel(const f16* __restrict__ q16, const f16* __restrict__ k16, const f16* __restrict__ v16,
                      const float* __restrict__ qs, const float* __restrict__ ks, const float* __restrict__ vs,
                      const float* __restrict__ nrope, const float* __restrict__ crope,
                      f16* __restrict__ qH, f16* __restrict__ kH, f16* __restrict__ vH) {
    const int r = blockIdx.x, h = blockIdx.y, d = threadIdx.x;
    const size_t src = (size_t)r * DIM_C + h * HD + d;
    float qv = (float)q16[src], kv = (float)k16[src], vv = (float)v16[src];
    float sq = qv * qv, sk = kv * kv, sv = vv * vv;
#pragma unroll
    for (int m = 1; m < 64; m <<= 1) {
        sq += __shfl_xor(sq, m);
        sk += __shfl_xor(sk, m);
        sv += __shfl_xor(sv, m);
    }
    __shared__ float part[3][2];
    const int wid = d >> 6;
    if ((d & 63) == 0) { part[0][wid] = sq; part[1][wid] = sk; part[2][wid] = sv; }
    __syncthreads();
    float rq = rsqrtf((part[0][0] + part[0][1]) * (1.0f / 128.0f) + 1e-6f);
    float rk = rsqrtf((part[1][0] + part[1][1]) * (1.0f / 128.0f) + 1e-6f);
    float rv = rsqrtf((part[2][0] + part[2][1]) * (1.0f / 128.0f) + 1e-6f);
    float qn = qv * rq * qs[d];
    float kn = kv * rk * ks[d];
    float vn = vv * rv * vs[d];
    __shared__ float shq[128], shk[128];
    shq[d] = qn; shk[d] = kn;
    __syncthreads();
    float rotq = (d < 64) ? -shq[d + 64] : shq[d - 64];
    float rotk = (d < 64) ? -shk[d + 64] : shk[d - 64];
    const float* rp = (r < L_NZ) ? (nrope + (size_t)r * HD) : (crope + (size_t)(r - L_NZ) * HD);
    float fr = rp[d];
    float c = cosf(fr), s = sinf(fr);
    const size_t dst = ((size_t)h * L_TOT + r) * HD + d;
    qH[dst] = (f16)((qn * c + rotq * s) * 0.08838834764831845f);  // 1/sqrt(128)
    kH[dst] = (f16)(kn * c + rotk * s);
    vH[dst] = (f16)vn;
}

// ---------------------------------------------------------------- flash attention v2
// grid (24 qblocks, 16 heads), 256 thr = 4 waves, wave = 32 queries, 64-key LDS-staged tiles.
// K tile [64][128] f16, rows 256B, 16B-chunk c stored at c ^ (r&15) (swizzle via global src).
// V tile = V^T [128d][64k] packed as 64 d-pairs x 256B, chunk g10=(d&1)*8+kchunk stored at
// g10 ^ (pair&15). Both swizzles are involutions; read applies the same XOR.
__global__ __launch_bounds__(256, 2)
void flash_kernel(const f16* __restrict__ qH, const f16* __restrict__ kH,
                  const f16* __restrict__ vT, f16* __restrict__ xH) {
    __shared__ __align__(16) f16 lds_k[64 * 128];
    __shared__ __align__(16) f16 lds_v[64 * 128];
    __shared__ __align__(16) f16 p_lds[4][32][72];
    const int tid = threadIdx.x;
    const int lane = tid & 63, w = tid >> 6;
    const int h = blockIdx.y;
    const int q0 = blockIdx.x * 128 + w * 32;
    const int rl = lane & 15, rq = lane >> 4;

    // Q fragments (A operand): 2 q-tiles x 4 k-slices, loaded once from global
    half8 aq[2][4];
    const f16* qbase = qH + ((size_t)h * L_TOT + q0) * HD;
#pragma unroll
    for (int qt = 0; qt < 2; ++qt)
#pragma unroll
        for (int kc = 0; kc < 4; ++kc)
            aq[qt][kc] = *(const half8*)(qbase + (size_t)(qt * 16 + rl) * HD + kc * 32 + rq * 8);

    floatx4 acc[2][8] = {};
    float m_run[2][4], l_run[2][4];
#pragma unroll
    for (int qt = 0; qt < 2; ++qt)
#pragma unroll
        for (int j = 0; j < 4; ++j) { m_run[qt][j] = -1e30f; l_run[qt][j] = 0.f; }

    const int kLo = (blockIdx.x >= 16) ? L_NZ : 0;   // cond queries attend only cond keys
    const f16* khead = kH + (size_t)h * L_TOT * HD;
    const f16* vhead = vT + (size_t)h * HD * L_TOT;

    for (int kb = kLo; kb < L_TOT; kb += 64) {
        __syncthreads();   // previous tile's compute done before overwrite
        // stage K tile: slot i (16B): row r=i>>4, pos c=i&15 holds global chunk c^(r&15)
#pragma unroll
        for (int is = 0; is < 4; ++is) {
            int i = is * 256 + tid;
            int r = i >> 4, c = i & 15;
            gl_lds16(khead + (size_t)(kb + r) * HD + ((c ^ (r & 15)) * 8),
                     lds_k + (is * 256 + w * 64) * 8);
        }
        // stage V tile: slot i: pair=i>>4, pos c10=i&15 holds global chunk g10=c10^(pair&15),
        // where g10 encodes d = pair*2 + (g10>>3), kchunk = g10&7
#pragma unroll
        for (int is = 0; is < 4; ++is) {
            int i = is * 256 + tid;
            int pair = i >> 4, c10 = i & 15;
            int g10 = c10 ^ (pair & 15);
            int d = pair * 2 + (g10 >> 3), kchunk = g10 & 7;
            gl_lds16(vhead + (size_t)d * L_TOT + kb + kchunk * 8,
                     lds_v + (is * 256 + w * 64) * 8);
        }
        __syncthreads();   // drains vmcnt -> staged data visible

        // QK^T: sacc[qt][kf], keys kf*16+(lane&15), q rows qt*16+(rq*4+j)
        floatx4 sacc[2][4] = {};
#pragma unroll
        for (int kf = 0; kf < 4; ++kf) {
            int r = kf * 16 + rl;
#pragma unroll
            for (int kc = 0; kc < 4; ++kc) {
                half8 bk = *(const half8*)(lds_k + r * 128 + (((kc * 4 + rq) ^ (r & 15)) * 8));
                sacc[0][kf] = __builtin_amdgcn_mfma_f32_16x16x32_f16(aq[0][kc], bk, sacc[0][kf], 0, 0, 0);
                sacc[1][kf] = __builtin_amdgcn_mfma_f32_16x16x32_f16(aq[1][kc], bk, sacc[1][kf], 0, 0, 0);
            }
        }
        // online softmax over the 64 keys
#pragma unroll
        for (int qt = 0; qt < 2; ++qt)
#pragma unroll
            for (int j = 0; j < 4; ++j) {
                float bm = fmaxf(fmaxf(sacc[qt][0][j], sacc[qt][1][j]),
                                 fmaxf(sacc[qt][2][j], sacc[qt][3][j]));
                bm = fmaxf(bm, __shfl_xor(bm, 1));
                bm = fmaxf(bm, __shfl_xor(bm, 2));
                bm = fmaxf(bm, __shfl_xor(bm, 4));
                bm = fmaxf(bm, __shfl_xor(bm, 8));
                float mn = fmaxf(m_run[qt][j], bm);
                float sc = __expf(m_run[qt][j] - mn);
                m_run[qt][j] = mn;
                float p0 = __expf(sacc[qt][0][j] - mn);
                float p1 = __expf(sacc[qt][1][j] - mn);
                float p2 = __expf(sacc[qt][2][j] - mn);
                float p3 = __expf(sacc[qt][3][j] - mn);
                float ps = p0 + p1 + p2 + p3;
                ps += __shfl_xor(ps, 1); ps += __shfl_xor(ps, 2);
                ps += __shfl_xor(ps, 4); ps += __shfl_xor(ps, 8);
                l_run[qt][j] = l_run[qt][j] * sc + ps;
#pragma unroll
                for (int dt = 0; dt < 8; ++dt) acc[qt][dt][j] *= sc;
                int pr = qt * 16 + rq * 4 + j;
                p_lds[w][pr][0 * 16 + rl] = (f16)p0;
                p_lds[w][pr][1 * 16 + rl] = (f16)p1;
                p_lds[w][pr][2 * 16 + rl] = (f16)p2;
                p_lds[w][pr][3 * 16 + rl] = (f16)p3;
            }
        // PV: A = P[32q][64k] via p_lds, B = V^T from lds_v
#pragma unroll
        for (int kc = 0; kc < 2; ++kc) {
            half8 ap0 = *(const half8*)(&p_lds[w][0 * 16 + rl][kc * 32 + rq * 8]);
            half8 ap1 = *(const half8*)(&p_lds[w][1 * 16 + rl][kc * 32 + rq * 8]);
#pragma unroll
            for (int dt = 0; dt < 8; ++dt) {
                int d = dt * 16 + rl;
                int g10 = (d & 1) * 8 + kc * 4 + rq;
                half8 bv = *(const half8*)(lds_v + (d >> 1) * 128 + ((g10 ^ ((d >> 1) & 15)) * 8));
                acc[0][dt] = __builtin_amdgcn_mfma_f32_16x16x32_f16(ap0, bv, acc[0][dt], 0, 0, 0);
                acc[1][dt] = __builtin_amdgcn_mfma_f32_16x16x32_f16(ap1, bv, acc[1][dt], 0, 0, 0);
            }
        }
    }

    // epilogue
#pragma unroll
    for (int qt = 0; qt < 2; ++qt)
#pragma unroll
        for (int j = 0; j < 4; ++j) {
            float li = 1.0f / l_run[qt][j];
            int row = q0 + qt * 16 + rq * 4 + j;
#pragma unroll
            for (int dt = 0; dt < 8; ++dt)
                xH[(size_t)row * DIM_C + h * HD + dt * 16 + rl] = (f16)(acc[qt][dt][j] * li);
        }
}

// ---------------------------------------------------------------- launch
extern "C" void kernel_launch(void* const* d_in, const int* in_sizes, int n_in,
                              void* d_out, int out_size, void* d_ws, size_t ws_size,
                              hipStream_t stream) {
    const float* noise = (const float*)d_in[0];
    const float* cond  = (const float*)d_in[1];
    const float* nrope = (const float*)d_in[2];
    const float* crope = (const float*)d_in[3];
    const float* Wq = (const float*)d_in[4];
    const float* Wk = (const float*)d_in[5];
    const float* Wv = (const float*)d_in[6];
    const float* Wo = (const float*)d_in[7];
    const float* bq = (const float*)d_in[8];
    const float* bk = (const float*)d_in[9];
    const float* bv = (const float*)d_in[10];
    const float* bo = (const float*)d_in[11];
    const float* qs = (const float*)d_in[12];
    const float* ks = (const float*)d_in[13];
    const float* vs = (const float*)d_in[14];
    const float* lqd = (const float*)d_in[15];
    const float* lqu = (const float*)d_in[16];
    const float* lkd = (const float*)d_in[17];
    const float* lku = (const float*)d_in[18];
    const float* lvd = (const float*)d_in[19];
    const float* lvu = (const float*)d_in[20];
    const float* lod = (const float*)d_in[21];
    const float* lou = (const float*)d_in[22];
    (void)in_sizes; (void)n_in; (void)out_size;

    char* ws = (char*)d_ws;
    const size_t SZ_LD = (size_t)L_TOT * DIM_C * sizeof(f16);   // 12.58 MB
    const size_t SZ_W  = (size_t)DIM_C * DIM_C * sizeof(f16);   //  8.39 MB
    size_t o = 0;
    auto take = [&](size_t b) { size_t r = o; o += (b + 255) & ~(size_t)255; return r; };
    f16* jointH   = (f16*)(ws + take(SZ_LD));
    f16* WTqkv    = (f16*)(ws + take(3 * SZ_W));
    f16* WT3      = (f16*)(ws + take(SZ_W));
    f16* downTqkv = (f16*)(ws + take((size_t)384 * 2048 * 2));
    f16* downTo   = (f16*)(ws + take((size_t)128 * 2048 * 2));
    f16* upT0     = (f16*)(ws + take((size_t)2048 * 128 * 2));
    f16* upT1     = (f16*)(ws + take((size_t)2048 * 128 * 2));
    f16* upT2     = (f16*)(ws + take((size_t)2048 * 128 * 2));
    f16* upTo     = (f16*)(ws + take((size_t)2048 * 128 * 2));
    f16* q16      = (f16*)(ws + take(3 * SZ_LD));   // q16,k16,v16 contiguous (SPLIT3)
    f16* k16      = q16 + (size_t)L_TOT * DIM_C;
    f16* v16      = k16 + (size_t)L_TOT * DIM_C;
    f16* t_all    = (f16*)(ws + take((size_t)1024 * 384 * 2));
    f16* t_o      = (f16*)(ws + take((size_t)1024 * 128 * 2));
    f16* qHd      = (f16*)(ws + take(SZ_LD));
    f16* kHd      = (f16*)(ws + take(SZ_LD));
    f16* vHd      = (f16*)(ws + take(SZ_LD));
    f16* vTd      = (f16*)(ws + take(SZ_LD));
    f16* xH       = (f16*)(ws + take(SZ_LD));
    if (o > ws_size) {
        sentinel_kernel<<<1, 1, 0, stream>>>((float*)d_out);
        return;
    }

    // 1) casts + weight transposes (B^T layout, f16)
    cast_f32_f16<<<dim3((2048 * 2048) / 1024), 256, 0, stream>>>(noise, jointH, 2048 * 2048);
    cast_f32_f16<<<dim3((1024 * 2048) / 1024), 256, 0, stream>>>(cond, jointH + (size_t)2048 * 2048, 1024 * 2048);
    transpose_cast<float><<<dim3(64, 64, 1), 256, 0, stream>>>(Wq, WTqkv,                          2048, 2048, 0, 0);
    transpose_cast<float><<<dim3(64, 64, 1), 256, 0, stream>>>(Wk, WTqkv + (size_t)2048 * 2048,     2048, 2048, 0, 0);
    transpose_cast<float><<<dim3(64, 64, 1), 256, 0, stream>>>(Wv, WTqkv + (size_t)2 * 2048 * 2048, 2048, 2048, 0, 0);
    transpose_cast<float><<<dim3(64, 64, 1), 256, 0, stream>>>(Wo, WT3, 2048, 2048, 0, 0);
    transpose_cast<float><<<dim3(4, 64, 1), 256, 0, stream>>>(lqd, downTqkv,                      2048, 128, 0, 0);
    transpose_cast<float><<<dim3(4, 64, 1), 256, 0, stream>>>(lkd, downTqkv + (size_t)128 * 2048, 2048, 128, 0, 0);
    transpose_cast<float><<<dim3(4, 64, 1), 256, 0, stream>>>(lvd, downTqkv + (size_t)256 * 2048, 2048, 128, 0, 0);
    transpose_cast<float><<<dim3(4, 64, 1), 256, 0, stream>>>(lod, downTo, 2048, 128, 0, 0);
    transpose_cast<float><<<dim3(64, 4, 1), 256, 0, stream>>>(lqu, upT0, 128, 2048, 0, 0);
    transpose_cast<float><<<dim3(64, 4, 1), 256, 0, stream>>>(lku, upT1, 128, 2048, 0, 0);
    transpose_cast<float><<<dim3(64, 4, 1), 256, 0, stream>>>(lvu, upT2, 128, 2048, 0, 0);
    transpose_cast<float><<<dim3(64, 4, 1), 256, 0, stream>>>(lou, upTo, 128, 2048, 0, 0);

    // 2) merged QKV projection (+per-chunk bias), then LoRA (cond rows only)
    gemm_tn<1, 0, 1, 1><<<dim3(6144 / 128, 3072 / 128), 256, 0, stream>>>(
        jointH, WTqkv, q16, bq, bk, bv, 3072, 6144, 2048, 2048, 2048, 2048, 1.0f);
    // stacked lora-down: t_all[1024][384] = joint_cond @ [Wdq|Wdk|Wdv]  (scale = 128/128 = 1)
    gemm_tn<1, 0, 0, 0><<<dim3(3, 8), 256, 0, stream>>>(jointH + (size_t)2048 * 2048, downTqkv, t_all,
                                                        nullptr, nullptr, nullptr,
                                                        1024, 384, 2048, 2048, 2048, 384, 1.0f);
    dim3 gup(2048 / 128, 1024 / 128);
    gemm_tn<1, 1, 0, 0><<<gup, 256, 0, stream>>>(t_all + 0,   upT0, q16 + (size_t)2048 * 2048,
                                                 nullptr, nullptr, nullptr, 1024, 2048, 128, 384, 128, 2048, 1.0f);
    gemm_tn<1, 1, 0, 0><<<gup, 256, 0, stream>>>(t_all + 128, upT1, k16 + (size_t)2048 * 2048,
                                                 nullptr, nullptr, nullptr, 1024, 2048, 128, 384, 128, 2048, 1.0f);
    gemm_tn<1, 1, 0, 0><<<gup, 256, 0, stream>>>(t_all + 256, upT2, v16 + (size_t)2048 * 2048,
                                                 nullptr, nullptr, nullptr, 1024, 2048, 128, 384, 128, 2048, 1.0f);

    // 3) RMS norm + RoPE -> head-major; transpose v per head
    norm_rope_kernel<<<dim3(3072, 16), 128, 0, stream>>>(q16, k16, v16, qs, ks, vs, nrope, crope, qHd, kHd, vHd);
    transpose_cast<f16><<<dim3(4, 96, 16), 256, 0, stream>>>(vHd, vTd, 3072, 128,
                                                             (long long)3072 * 128, (long long)128 * 3072);

    // 4) flash attention -> xH [L][2048]
    flash_kernel<<<dim3(24, 16), 256, 0, stream>>>(qHd, kHd, vTd, xH);

    // 5) output projection (+bias) and LoRA-o
    gemm_tn<0, 0, 1, 0><<<dim3(16, 24), 256, 0, stream>>>(xH, WT3, d_out, bo, nullptr, nullptr,
                                                          3072, 2048, 2048, 2048, 2048, 2048, 1.0f);
    gemm_tn<1, 0, 0, 0><<<dim3(1, 8), 256, 0, stream>>>(xH + (size_t)2048 * 2048, downTo, t_o,
                                                        nullptr, nullptr, nullptr,
                                                        1024, 128, 2048, 2048, 2048, 128, 1.0f);
    gemm_tn<0, 1, 0, 0><<<gup, 256, 0, stream>>>(t_o, upTo, (float*)d_out + (size_t)2048 * 2048,
                                                 nullptr, nullptr, nullptr,
                                                 1024, 2048, 128, 128, 128, 2048, 1.0f);
}

// Round 6
// 555.073 us; speedup vs baseline: 1.4737x; 1.0101x over previous
//
#include <hip/hip_runtime.h>

typedef _Float16 f16;
typedef _Float16 half8 __attribute__((ext_vector_type(8)));
typedef float floatx4 __attribute__((ext_vector_type(4)));

#define L_TOT   3072
#define L_NZ    2048
#define DIM_C   2048
#define NH      16
#define HD      128

// ---------------------------------------------------------------- helpers
__device__ __forceinline__ void gl_lds16(const f16* g, f16* l) {
    // async global->LDS, 16B per lane; LDS dest = wave-uniform base + lane*16
    __builtin_amdgcn_global_load_lds((__attribute__((address_space(1))) void*)g,
                                     (__attribute__((address_space(3))) void*)l,
                                     16, 0, 0);
}

__global__ void sentinel_kernel(float* out) { out[0] = 1.0e6f; }

// ---------------------------------------------------------------- cast f32 -> f16
__global__ __launch_bounds__(256)
void cast_f32_f16(const float* __restrict__ in, f16* __restrict__ out, int n) {
    int i = (blockIdx.x * 256 + threadIdx.x) * 4;
    if (i + 3 < n) {
        float4 v = *(const float4*)(in + i);
        out[i+0] = (f16)v.x; out[i+1] = (f16)v.y;
        out[i+2] = (f16)v.z; out[i+3] = (f16)v.w;
    }
}

// ---------------------------------------------------------------- transpose (+cast) -> f16, out[c][r] = in[r][c]
template<typename TIN>
__global__ __launch_bounds__(256)
void transpose_cast(const TIN* __restrict__ in, f16* __restrict__ out,
                    int R, int C, long long inBatch, long long outBatch) {
    in  += (long long)blockIdx.z * inBatch;
    out += (long long)blockIdx.z * outBatch;
    __shared__ f16 tile[32][33];
    int x = threadIdx.x & 31, y0 = threadIdx.x >> 5;
    int r0 = blockIdx.y * 32, c0 = blockIdx.x * 32;
#pragma unroll
    for (int i = 0; i < 4; ++i) {
        int y = y0 + i * 8;
        tile[y][x] = (f16)(float)in[(size_t)(r0 + y) * C + (c0 + x)];
    }
    __syncthreads();
#pragma unroll
    for (int i = 0; i < 4; ++i) {
        int y = y0 + i * 8;
        out[(size_t)(c0 + y) * R + (r0 + x)] = tile[x][y];
    }
}

// ---------------------------------------------------------------- GEMM C[M][N] = A[M][K] * BT[N][K]^T  (f16 in, f32 acc)
// 128x128 tile, BK=32, 4 waves (2x2), each wave 64x64 via 4x4 16x16x32 MFMA frags.
// SPLIT3: N spans 3 chunks of 2048; chunk c writes to Cbase + c*3072*2048 with bias{0,1,2}.
template<int WRITE_HALF, int ACCUM, int ADD_BIAS, int SPLIT3>
__global__ __launch_bounds__(256)
void gemm_tn(const f16* __restrict__ A, const f16* __restrict__ BT,
             void* __restrict__ Cv,
             const float* __restrict__ bias0, const float* __restrict__ bias1,
             const float* __restrict__ bias2,
             int M, int N, int K, int lda, int ldb, int ldc, float cscale) {
    __shared__ __align__(16) f16 lds_a[128 * 32];
    __shared__ __align__(16) f16 lds_b[128 * 32];
    const int tid  = threadIdx.x;
    const int lane = tid & 63, wave = tid >> 6;
    const int m0 = blockIdx.y * 128, n0 = blockIdx.x * 128;
    const int wr = wave >> 1, wc = wave & 1;
    floatx4 acc[4][4] = {};

    int e0 = ((wave * 2 + 0) * 64 + lane) * 8;
    int e1 = ((wave * 2 + 1) * 64 + lane) * 8;
    int row0 = e0 >> 5, kk0 = e0 & 31;
    int row1 = e1 >> 5, kk1 = e1 & 31;
    const f16* gA0 = A  + (size_t)(m0 + row0) * lda + kk0;
    const f16* gA1 = A  + (size_t)(m0 + row1) * lda + kk1;
    const f16* gB0 = BT + (size_t)(n0 + row0) * ldb + kk0;
    const f16* gB1 = BT + (size_t)(n0 + row1) * ldb + kk1;
    f16* la0 = lds_a + (wave * 2 + 0) * 512;
    f16* la1 = lds_a + (wave * 2 + 1) * 512;
    f16* lb0 = lds_b + (wave * 2 + 0) * 512;
    f16* lb1 = lds_b + (wave * 2 + 1) * 512;

    const int rl = lane & 15, kq = (lane >> 4) * 8;

    for (int k0 = 0; k0 < K; k0 += 32) {
        if (k0) __syncthreads();
        gl_lds16(gA0, la0); gl_lds16(gA1, la1);
        gl_lds16(gB0, lb0); gl_lds16(gB1, lb1);
        gA0 += 32; gA1 += 32; gB0 += 32; gB1 += 32;
        __syncthreads();
        half8 af[4], bf[4];
#pragma unroll
        for (int m = 0; m < 4; ++m)
            af[m] = *(const half8*)(lds_a + (wr * 64 + m * 16 + rl) * 32 + kq);
#pragma unroll
        for (int n = 0; n < 4; ++n)
            bf[n] = *(const half8*)(lds_b + (wc * 64 + n * 16 + rl) * 32 + kq);
#pragma unroll
        for (int m = 0; m < 4; ++m)
#pragma unroll
            for (int n = 0; n < 4; ++n)
                acc[m][n] = __builtin_amdgcn_mfma_f32_16x16x32_f16(af[m], bf[n], acc[m][n], 0, 0, 0);
    }

    // epilogue: C col = lane&15, row = (lane>>4)*4 + j
    const int rq = lane >> 4;
    const float* bias = bias0;
    size_t cbase = 0;
    if (SPLIT3) {
        int chunk = n0 >> 11;
        bias = (chunk == 0) ? bias0 : ((chunk == 1) ? bias1 : bias2);
        cbase = (size_t)chunk * ((size_t)L_TOT * DIM_C);
    }
#pragma unroll
    for (int m = 0; m < 4; ++m) {
        int row = m0 + wr * 64 + m * 16 + rq * 4;
#pragma unroll
        for (int n = 0; n < 4; ++n) {
            int col = n0 + wc * 64 + n * 16 + rl;
            float badd = ADD_BIAS ? bias[SPLIT3 ? (col & 2047) : col] : 0.0f;
            int ccol = SPLIT3 ? (col & 2047) : col;
#pragma unroll
            for (int j = 0; j < 4; ++j) {
                float v = acc[m][n][j] * cscale + badd;
                size_t idx = cbase + (size_t)(row + j) * ldc + ccol;
                if (WRITE_HALF) {
                    f16* C = (f16*)Cv;
                    if (ACCUM) v += (float)C[idx];
                    C[idx] = (f16)v;
                } else {
                    float* C = (float*)Cv;
                    if (ACCUM) v += C[idx];
                    C[idx] = v;
                }
            }
        }
    }
}

// ---------------------------------------------------------------- RMS norm + RoPE, writes head-major q/k (q pre-scaled 1/sqrt(128)) and v
__global__ __launch_bounds__(128)
void norm_rope_kernel(const f16* __restrict__ q16, const f16* __restrict__ k16, const f16* __restrict__ v16,
                      const float* __restrict__ qs, const float* __restrict__ ks, const float* __restrict__ vs,
                      const float* __restrict__ nrope, const float* __restrict__ crope,
                      f16* __restrict__ qH, f16* __restrict__ kH, f16* __restrict__ vH) {
    const int r = blockIdx.x, h = blockIdx.y, d = threadIdx.x;
    const size_t src = (size_t)r * DIM_C + h * HD + d;
    float qv = (float)q16[src], kv = (float)k16[src], vv = (float)v16[src];
    float sq = qv * qv, sk = kv * kv, sv = vv * vv;
#pragma unroll
    for (int m = 1; m < 64; m <<= 1) {
        sq += __shfl_xor(sq, m);
        sk += __shfl_xor(sk, m);
        sv += __shfl_xor(sv, m);
    }
    __shared__ float part[3][2];
    const int wid = d >> 6;
    if ((d & 63) == 0) { part[0][wid] = sq; part[1][wid] = sk; part[2][wid] = sv; }
    __syncthreads();
    float rq = rsqrtf((part[0][0] + part[0][1]) * (1.0f / 128.0f) + 1e-6f);
    float rk = rsqrtf((part[1][0] + part[1][1]) * (1.0f / 128.0f) + 1e-6f);
    float rv = rsqrtf((part[2][0] + part[2][1]) * (1.0f / 128.0f) + 1e-6f);
    float qn = qv * rq * qs[d];
    float kn = kv * rk * ks[d];
    float vn = vv * rv * vs[d];
    __shared__ float shq[128], shk[128];
    shq[d] = qn; shk[d] = kn;
    __syncthreads();
    float rotq = (d < 64) ? -shq[d + 64] : shq[d - 64];
    float rotk = (d < 64) ? -shk[d + 64] : shk[d - 64];
    const float* rp = (r < L_NZ) ? (nrope + (size_t)r * HD) : (crope + (size_t)(r - L_NZ) * HD);
    float fr = rp[d];
    float c = cosf(fr), s = sinf(fr);
    const size_t dst = ((size_t)h * L_TOT + r) * HD + d;
    qH[dst] = (f16)((qn * c + rotq * s) * 0.08838834764831845f);  // 1/sqrt(128)
    kH[dst] = (f16)(kn * c + rotk * s);
    vH[dst] = (f16)vn;
}

// ---------------------------------------------------------------- flash attention v3
// 1D grid 384 blocks, XCD-clustered: xcd=bid&7 gets heads {xcd, xcd+8} whole (K/V stays in
// one XCD L2). 4 waves x 32 queries. K double-buffered + counted vmcnt pipeline:
//   issue V(t), K(t+1) -> vmcnt(8) [K(t) ready] -> bar -> QK+softmax -> vmcnt(4) [V(t)
//   ready] -> bar -> PV -> bar.  K(t+1) stays in flight across the whole iteration.
// Swizzles identical to v2 (XOR involution, applied on global-source side).
__global__ __launch_bounds__(256, 2)
void flash_kernel(const f16* __restrict__ qH, const f16* __restrict__ kH,
                  const f16* __restrict__ vT, f16* __restrict__ xH) {
    __shared__ __align__(16) f16 lds_k[2][64 * 128];
    __shared__ __align__(16) f16 lds_v[64 * 128];
    __shared__ __align__(16) f16 p_lds[4][32][72];
    const int tid = threadIdx.x;
    const int lane = tid & 63, w = tid >> 6;
    const int bid = blockIdx.x;
    const int xcd = bid & 7, rr = bid >> 3;     // rr in [0,48)
    const int h = xcd + 8 * (rr / 24);
    const int qb = rr % 24;
    const int q0 = qb * 128 + w * 32;
    const int rl = lane & 15, rq = lane >> 4;

    // Q fragments (A operand): 2 q-tiles x 4 k-slices, loaded once from global
    half8 aq[2][4];
    const f16* qbase = qH + ((size_t)h * L_TOT + q0) * HD;
#pragma unroll
    for (int qt = 0; qt < 2; ++qt)
#pragma unroll
        for (int kc = 0; kc < 4; ++kc)
            aq[qt][kc] = *(const half8*)(qbase + (size_t)(qt * 16 + rl) * HD + kc * 32 + rq * 8);

    floatx4 acc[2][8] = {};
    float m_run[2][4], l_run[2][4];
#pragma unroll
    for (int qt = 0; qt < 2; ++qt)
#pragma unroll
        for (int j = 0; j < 4; ++j) { m_run[qt][j] = -1e30f; l_run[qt][j] = 0.f; }

    const int kLo = (qb >= 16) ? L_NZ : 0;   // cond queries attend only cond keys
    const f16* khead = kH + (size_t)h * L_TOT * HD;
    const f16* vhead = vT + (size_t)h * HD * L_TOT;

    auto stageK = [&](int kb, int pb) {
#pragma unroll
        for (int is = 0; is < 4; ++is) {
            int i = is * 256 + tid;
            int r = i >> 4, c = i & 15;
            gl_lds16(khead + (size_t)(kb + r) * HD + ((c ^ (r & 15)) * 8),
                     &lds_k[pb][0] + (is * 256 + w * 64) * 8);
        }
    };
    auto stageV = [&](int kb) {
#pragma unroll
        for (int is = 0; is < 4; ++is) {
            int i = is * 256 + tid;
            int pair = i >> 4, c10 = i & 15;
            int g10 = c10 ^ (pair & 15);
            int d = pair * 2 + (g10 >> 3), kchunk = g10 & 7;
            gl_lds16(vhead + (size_t)d * L_TOT + kb + kchunk * 8,
                     lds_v + (is * 256 + w * 64) * 8);
        }
    };

    asm volatile("s_waitcnt vmcnt(0)" ::: "memory");   // drain Q loads -> deterministic counts
    stageK(kLo, 0);                                     // prefetch K(0); 4 issues in flight
    int p = 0;
    for (int kb = kLo; kb < L_TOT; kb += 64) {
        const int kbn = (kb + 64 < L_TOT) ? (kb + 64) : kLo;  // dummy refetch on last iter
        stageV(kb);                                     // +4 issues
        stageK(kbn, p ^ 1);                             // +4 issues
        asm volatile("s_waitcnt vmcnt(8)" ::: "memory");       // own K(kb) landed
        __builtin_amdgcn_s_barrier();                          // all waves' K(kb) landed
        __builtin_amdgcn_sched_barrier(0);

        // QK^T on lds_k[p]: sacc[qt][kf], keys kf*16+rl, q rows qt*16+(rq*4+j)
        const f16* kbase = &lds_k[p][0];
        floatx4 sacc[2][4] = {};
#pragma unroll
        for (int kf = 0; kf < 4; ++kf) {
            int r = kf * 16 + rl;
#pragma unroll
            for (int kc = 0; kc < 4; ++kc) {
                half8 bk = *(const half8*)(kbase + r * 128 + (((kc * 4 + rq) ^ (r & 15)) * 8));
                sacc[0][kf] = __builtin_amdgcn_mfma_f32_16x16x32_f16(aq[0][kc], bk, sacc[0][kf], 0, 0, 0);
                sacc[1][kf] = __builtin_amdgcn_mfma_f32_16x16x32_f16(aq[1][kc], bk, sacc[1][kf], 0, 0, 0);
            }
        }
        // online softmax over the 64 keys (p_lds is per-wave: no cross-wave hazard)
#pragma unroll
        for (int qt = 0; qt < 2; ++qt)
#pragma unroll
            for (int j = 0; j < 4; ++j) {
                float bm = fmaxf(fmaxf(sacc[qt][0][j], sacc[qt][1][j]),
                                 fmaxf(sacc[qt][2][j], sacc[qt][3][j]));
                bm = fmaxf(bm, __shfl_xor(bm, 1));
                bm = fmaxf(bm, __shfl_xor(bm, 2));
                bm = fmaxf(bm, __shfl_xor(bm, 4));
                bm = fmaxf(bm, __shfl_xor(bm, 8));
                float mn = fmaxf(m_run[qt][j], bm);
                float sc = __expf(m_run[qt][j] - mn);
                m_run[qt][j] = mn;
                float p0 = __expf(sacc[qt][0][j] - mn);
                float p1 = __expf(sacc[qt][1][j] - mn);
                float p2 = __expf(sacc[qt][2][j] - mn);
                float p3 = __expf(sacc[qt][3][j] - mn);
                float ps = p0 + p1 + p2 + p3;
                ps += __shfl_xor(ps, 1); ps += __shfl_xor(ps, 2);
                ps += __shfl_xor(ps, 4); ps += __shfl_xor(ps, 8);
                l_run[qt][j] = l_run[qt][j] * sc + ps;
#pragma unroll
                for (int dt = 0; dt < 8; ++dt) acc[qt][dt][j] *= sc;
                int pr = qt * 16 + rq * 4 + j;
                p_lds[w][pr][0 * 16 + rl] = (f16)p0;
                p_lds[w][pr][1 * 16 + rl] = (f16)p1;
                p_lds[w][pr][2 * 16 + rl] = (f16)p2;
                p_lds[w][pr][3 * 16 + rl] = (f16)p3;
            }

        asm volatile("s_waitcnt vmcnt(4)" ::: "memory");       // own V(kb) landed (K(kbn) in flight)
        __builtin_amdgcn_s_barrier();                          // all waves' V(kb) landed
        __builtin_amdgcn_sched_barrier(0);

        // PV: A = P[32q][64k] via p_lds, B = V^T from lds_v
#pragma unroll
        for (int kc = 0; kc < 2; ++kc) {
            half8 ap0 = *(const half8*)(&p_lds[w][0 * 16 + rl][kc * 32 + rq * 8]);
            half8 ap1 = *(const half8*)(&p_lds[w][1 * 16 + rl][kc * 32 + rq * 8]);
#pragma unroll
            for (int dt = 0; dt < 8; ++dt) {
                int d = dt * 16 + rl;
                int g10 = (d & 1) * 8 + kc * 4 + rq;
                half8 bv = *(const half8*)(lds_v + (d >> 1) * 128 + ((g10 ^ ((d >> 1) & 15)) * 8));
                acc[0][dt] = __builtin_amdgcn_mfma_f32_16x16x32_f16(ap0, bv, acc[0][dt], 0, 0, 0);
                acc[1][dt] = __builtin_amdgcn_mfma_f32_16x16x32_f16(ap1, bv, acc[1][dt], 0, 0, 0);
            }
        }
        __builtin_amdgcn_s_barrier();     // all waves done reading lds_v before next stageV
        p ^= 1;
    }

    // epilogue
#pragma unroll
    for (int qt = 0; qt < 2; ++qt)
#pragma unroll
        for (int j = 0; j < 4; ++j) {
            float li = 1.0f / l_run[qt][j];
            int row = q0 + qt * 16 + rq * 4 + j;
#pragma unroll
            for (int dt = 0; dt < 8; ++dt)
                xH[(size_t)row * DIM_C + h * HD + dt * 16 + rl] = (f16)(acc[qt][dt][j] * li);
        }
}

// ---------------------------------------------------------------- launch
extern "C" void kernel_launch(void* const* d_in, const int* in_sizes, int n_in,
                              void* d_out, int out_size, void* d_ws, size_t ws_size,
                              hipStream_t stream) {
    const float* noise = (const float*)d_in[0];
    const float* cond  = (const float*)d_in[1];
    const float* nrope = (const float*)d_in[2];
    const float* crope = (const float*)d_in[3];
    const float* Wq = (const float*)d_in[4];
    const float* Wk = (const float*)d_in[5];
    const float* Wv = (const float*)d_in[6];
    const float* Wo = (const float*)d_in[7];
    const float* bq = (const float*)d_in[8];
    const float* bk = (const float*)d_in[9];
    const float* bv = (const float*)d_in[10];
    const float* bo = (const float*)d_in[11];
    const float* qs = (const float*)d_in[12];
    const float* ks = (const float*)d_in[13];
    const float* vs = (const float*)d_in[14];
    const float* lqd = (const float*)d_in[15];
    const float* lqu = (const float*)d_in[16];
    const float* lkd = (const float*)d_in[17];
    const float* lku = (const float*)d_in[18];
    const float* lvd = (const float*)d_in[19];
    const float* lvu = (const float*)d_in[20];
    const float* lod = (const float*)d_in[21];
    const float* lou = (const float*)d_in[22];
    (void)in_sizes; (void)n_in; (void)out_size;

    char* ws = (char*)d_ws;
    const size_t SZ_LD = (size_t)L_TOT * DIM_C * sizeof(f16);   // 12.58 MB
    const size_t SZ_W  = (size_t)DIM_C * DIM_C * sizeof(f16);   //  8.39 MB
    size_t o = 0;
    auto take = [&](size_t b) { size_t r = o; o += (b + 255) & ~(size_t)255; return r; };
    f16* jointH   = (f16*)(ws + take(SZ_LD));
    f16* WTqkv    = (f16*)(ws + take(3 * SZ_W));
    f16* WT3      = (f16*)(ws + take(SZ_W));
    f16* downTqkv = (f16*)(ws + take((size_t)384 * 2048 * 2));
    f16* downTo   = (f16*)(ws + take((size_t)128 * 2048 * 2));
    f16* upT0     = (f16*)(ws + take((size_t)2048 * 128 * 2));
    f16* upT1     = (f16*)(ws + take((size_t)2048 * 128 * 2));
    f16* upT2     = (f16*)(ws + take((size_t)2048 * 128 * 2));
    f16* upTo     = (f16*)(ws + take((size_t)2048 * 128 * 2));
    f16* q16      = (f16*)(ws + take(3 * SZ_LD));   // q16,k16,v16 contiguous (SPLIT3)
    f16* k16      = q16 + (size_t)L_TOT * DIM_C;
    f16* v16      = k16 + (size_t)L_TOT * DIM_C;
    f16* t_all    = (f16*)(ws + take((size_t)1024 * 384 * 2));
    f16* t_o      = (f16*)(ws + take((size_t)1024 * 128 * 2));
    f16* qHd      = (f16*)(ws + take(SZ_LD));
    f16* kHd      = (f16*)(ws + take(SZ_LD));
    f16* vHd      = (f16*)(ws + take(SZ_LD));
    f16* vTd      = (f16*)(ws + take(SZ_LD));
    f16* xH       = (f16*)(ws + take(SZ_LD));
    if (o > ws_size) {
        sentinel_kernel<<<1, 1, 0, stream>>>((float*)d_out);
        return;
    }

    // 1) casts + weight transposes (B^T layout, f16)
    cast_f32_f16<<<dim3((2048 * 2048) / 1024), 256, 0, stream>>>(noise, jointH, 2048 * 2048);
    cast_f32_f16<<<dim3((1024 * 2048) / 1024), 256, 0, stream>>>(cond, jointH + (size_t)2048 * 2048, 1024 * 2048);
    transpose_cast<float><<<dim3(64, 64, 1), 256, 0, stream>>>(Wq, WTqkv,                          2048, 2048, 0, 0);
    transpose_cast<float><<<dim3(64, 64, 1), 256, 0, stream>>>(Wk, WTqkv + (size_t)2048 * 2048,     2048, 2048, 0, 0);
    transpose_cast<float><<<dim3(64, 64, 1), 256, 0, stream>>>(Wv, WTqkv + (size_t)2 * 2048 * 2048, 2048, 2048, 0, 0);
    transpose_cast<float><<<dim3(64, 64, 1), 256, 0, stream>>>(Wo, WT3, 2048, 2048, 0, 0);
    transpose_cast<float><<<dim3(4, 64, 1), 256, 0, stream>>>(lqd, downTqkv,                      2048, 128, 0, 0);
    transpose_cast<float><<<dim3(4, 64, 1), 256, 0, stream>>>(lkd, downTqkv + (size_t)128 * 2048, 2048, 128, 0, 0);
    transpose_cast<float><<<dim3(4, 64, 1), 256, 0, stream>>>(lvd, downTqkv + (size_t)256 * 2048, 2048, 128, 0, 0);
    transpose_cast<float><<<dim3(4, 64, 1), 256, 0, stream>>>(lod, downTo, 2048, 128, 0, 0);
    transpose_cast<float><<<dim3(64, 4, 1), 256, 0, stream>>>(lqu, upT0, 128, 2048, 0, 0);
    transpose_cast<float><<<dim3(64, 4, 1), 256, 0, stream>>>(lku, upT1, 128, 2048, 0, 0);
    transpose_cast<float><<<dim3(64, 4, 1), 256, 0, stream>>>(lvu, upT2, 128, 2048, 0, 0);
    transpose_cast<float><<<dim3(64, 4, 1), 256, 0, stream>>>(lou, upTo, 128, 2048, 0, 0);

    // 2) merged QKV projection (+per-chunk bias), then LoRA (cond rows only)
    gemm_tn<1, 0, 1, 1><<<dim3(6144 / 128, 3072 / 128), 256, 0, stream>>>(
        jointH, WTqkv, q16, bq, bk, bv, 3072, 6144, 2048, 2048, 2048, 2048, 1.0f);
    // stacked lora-down: t_all[1024][384] = joint_cond @ [Wdq|Wdk|Wdv]  (scale = 128/128 = 1)
    gemm_tn<1, 0, 0, 0><<<dim3(3, 8), 256, 0, stream>>>(jointH + (size_t)2048 * 2048, downTqkv, t_all,
                                                        nullptr, nullptr, nullptr,
                                                        1024, 384, 2048, 2048, 2048, 384, 1.0f);
    dim3 gup(2048 / 128, 1024 / 128);
    gemm_tn<1, 1, 0, 0><<<gup, 256, 0, stream>>>(t_all + 0,   upT0, q16 + (size_t)2048 * 2048,
                                                 nullptr, nullptr, nullptr, 1024, 2048, 128, 384, 128, 2048, 1.0f);
    gemm_tn<1, 1, 0, 0><<<gup, 256, 0, stream>>>(t_all + 128, upT1, k16 + (size_t)2048 * 2048,
                                                 nullptr, nullptr, nullptr, 1024, 2048, 128, 384, 128, 2048, 1.0f);
    gemm_tn<1, 1, 0, 0><<<gup, 256, 0, stream>>>(t_all + 256, upT2, v16 + (size_t)2048 * 2048,
                                                 nullptr, nullptr, nullptr, 1024, 2048, 128, 384, 128, 2048, 1.0f);

    // 3) RMS norm + RoPE -> head-major; transpose v per head
    norm_rope_kernel<<<dim3(3072, 16), 128, 0, stream>>>(q16, k16, v16, qs, ks, vs, nrope, crope, qHd, kHd, vHd);
    transpose_cast<f16><<<dim3(4, 96, 16), 256, 0, stream>>>(vHd, vTd, 3072, 128,
                                                             (long long)3072 * 128, (long long)128 * 3072);

    // 4) flash attention -> xH [L][2048]  (1D grid, XCD-clustered decode inside)
    flash_kernel<<<dim3(384), 256, 0, stream>>>(qHd, kHd, vTd, xH);

    // 5) output projection (+bias) and LoRA-o
    gemm_tn<0, 0, 1, 0><<<dim3(16, 24), 256, 0, stream>>>(xH, WT3, d_out, bo, nullptr, nullptr,
                                                          3072, 2048, 2048, 2048, 2048, 2048, 1.0f);
    gemm_tn<1, 0, 0, 0><<<dim3(1, 8), 256, 0, stream>>>(xH + (size_t)2048 * 2048, downTo, t_o,
                                                        nullptr, nullptr, nullptr,
                                                        1024, 128, 2048, 2048, 2048, 128, 1.0f);
    gemm_tn<0, 1, 0, 0><<<gup, 256, 0, stream>>>(t_o, upTo, (float*)d_out + (size_t)2048 * 2048,
                                                 nullptr, nullptr, nullptr,
                                                 1024, 2048, 128, 128, 128, 2048, 1.0f);
}

// Round 7
// 463.543 us; speedup vs baseline: 1.7647x; 1.1975x over previous
//
#include <hip/hip_runtime.h>

typedef _Float16 f16;
typedef _Float16 half8 __attribute__((ext_vector_type(8)));
typedef float floatx4 __attribute__((ext_vector_type(4)));

#define L_TOT   3072
#define L_NZ    2048
#define DIM_C   2048
#define NH      16
#define HD      128

// ---------------------------------------------------------------- helpers
__device__ __forceinline__ void gl_lds16(const f16* g, f16* l) {
    // async global->LDS, 16B per lane; LDS dest = wave-uniform base + lane*16
    __builtin_amdgcn_global_load_lds((__attribute__((address_space(1))) void*)g,
                                     (__attribute__((address_space(3))) void*)l,
                                     16, 0, 0);
}

__global__ void sentinel_kernel(float* out) { out[0] = 1.0e6f; }

// ---------------------------------------------------------------- cast f32 -> f16
__global__ __launch_bounds__(256)
void cast_f32_f16(const float* __restrict__ in, f16* __restrict__ out, int n) {
    int i = (blockIdx.x * 256 + threadIdx.x) * 4;
    if (i + 3 < n) {
        float4 v = *(const float4*)(in + i);
        out[i+0] = (f16)v.x; out[i+1] = (f16)v.y;
        out[i+2] = (f16)v.z; out[i+3] = (f16)v.w;
    }
}

// ---------------------------------------------------------------- transpose (+cast) -> f16, out[c][r] = in[r][c]
template<typename TIN>
__global__ __launch_bounds__(256)
void transpose_cast(const TIN* __restrict__ in, f16* __restrict__ out,
                    int R, int C, long long inBatch, long long outBatch) {
    in  += (long long)blockIdx.z * inBatch;
    out += (long long)blockIdx.z * outBatch;
    __shared__ f16 tile[32][33];
    int x = threadIdx.x & 31, y0 = threadIdx.x >> 5;
    int r0 = blockIdx.y * 32, c0 = blockIdx.x * 32;
#pragma unroll
    for (int i = 0; i < 4; ++i) {
        int y = y0 + i * 8;
        tile[y][x] = (f16)(float)in[(size_t)(r0 + y) * C + (c0 + x)];
    }
    __syncthreads();
#pragma unroll
    for (int i = 0; i < 4; ++i) {
        int y = y0 + i * 8;
        out[(size_t)(c0 + y) * R + (r0 + x)] = tile[x][y];
    }
}

// ---------------------------------------------------------------- GEMM C[M][N] = A[M][K] * BT[N][K]^T  (f16 in, f32 acc)
// 128x128 tile, BK=32, 4 waves (2x2), each wave 64x64 via 4x4 16x16x32 MFMA frags.
// SPLIT3: N spans 3 chunks of 2048; chunk c writes to Cbase + c*3072*2048 with bias{0,1,2}.
template<int WRITE_HALF, int ACCUM, int ADD_BIAS, int SPLIT3>
__global__ __launch_bounds__(256)
void gemm_tn(const f16* __restrict__ A, const f16* __restrict__ BT,
             void* __restrict__ Cv,
             const float* __restrict__ bias0, const float* __restrict__ bias1,
             const float* __restrict__ bias2,
             int M, int N, int K, int lda, int ldb, int ldc, float cscale) {
    __shared__ __align__(16) f16 lds_a[128 * 32];
    __shared__ __align__(16) f16 lds_b[128 * 32];
    const int tid  = threadIdx.x;
    const int lane = tid & 63, wave = tid >> 6;
    const int m0 = blockIdx.y * 128, n0 = blockIdx.x * 128;
    const int wr = wave >> 1, wc = wave & 1;
    floatx4 acc[4][4] = {};

    int e0 = ((wave * 2 + 0) * 64 + lane) * 8;
    int e1 = ((wave * 2 + 1) * 64 + lane) * 8;
    int row0 = e0 >> 5, kk0 = e0 & 31;
    int row1 = e1 >> 5, kk1 = e1 & 31;
    const f16* gA0 = A  + (size_t)(m0 + row0) * lda + kk0;
    const f16* gA1 = A  + (size_t)(m0 + row1) * lda + kk1;
    const f16* gB0 = BT + (size_t)(n0 + row0) * ldb + kk0;
    const f16* gB1 = BT + (size_t)(n0 + row1) * ldb + kk1;
    f16* la0 = lds_a + (wave * 2 + 0) * 512;
    f16* la1 = lds_a + (wave * 2 + 1) * 512;
    f16* lb0 = lds_b + (wave * 2 + 0) * 512;
    f16* lb1 = lds_b + (wave * 2 + 1) * 512;

    const int rl = lane & 15, kq = (lane >> 4) * 8;

    for (int k0 = 0; k0 < K; k0 += 32) {
        if (k0) __syncthreads();
        gl_lds16(gA0, la0); gl_lds16(gA1, la1);
        gl_lds16(gB0, lb0); gl_lds16(gB1, lb1);
        gA0 += 32; gA1 += 32; gB0 += 32; gB1 += 32;
        __syncthreads();
        half8 af[4], bf[4];
#pragma unroll
        for (int m = 0; m < 4; ++m)
            af[m] = *(const half8*)(lds_a + (wr * 64 + m * 16 + rl) * 32 + kq);
#pragma unroll
        for (int n = 0; n < 4; ++n)
            bf[n] = *(const half8*)(lds_b + (wc * 64 + n * 16 + rl) * 32 + kq);
#pragma unroll
        for (int m = 0; m < 4; ++m)
#pragma unroll
            for (int n = 0; n < 4; ++n)
                acc[m][n] = __builtin_amdgcn_mfma_f32_16x16x32_f16(af[m], bf[n], acc[m][n], 0, 0, 0);
    }

    // epilogue: C col = lane&15, row = (lane>>4)*4 + j
    const int rq = lane >> 4;
    const float* bias = bias0;
    size_t cbase = 0;
    if (SPLIT3) {
        int chunk = n0 >> 11;
        bias = (chunk == 0) ? bias0 : ((chunk == 1) ? bias1 : bias2);
        cbase = (size_t)chunk * ((size_t)L_TOT * DIM_C);
    }
#pragma unroll
    for (int m = 0; m < 4; ++m) {
        int row = m0 + wr * 64 + m * 16 + rq * 4;
#pragma unroll
        for (int n = 0; n < 4; ++n) {
            int col = n0 + wc * 64 + n * 16 + rl;
            float badd = ADD_BIAS ? bias[SPLIT3 ? (col & 2047) : col] : 0.0f;
            int ccol = SPLIT3 ? (col & 2047) : col;
#pragma unroll
            for (int j = 0; j < 4; ++j) {
                float v = acc[m][n][j] * cscale + badd;
                size_t idx = cbase + (size_t)(row + j) * ldc + ccol;
                if (WRITE_HALF) {
                    f16* C = (f16*)Cv;
                    if (ACCUM) v += (float)C[idx];
                    C[idx] = (f16)v;
                } else {
                    float* C = (float*)Cv;
                    if (ACCUM) v += C[idx];
                    C[idx] = v;
                }
            }
        }
    }
}

// ---------------------------------------------------------------- RMS norm + RoPE, writes head-major q/k (q pre-scaled 1/sqrt(128)) and v
__global__ __launch_bounds__(128)
void norm_rope_kernel(const f16* __restrict__ q16, const f16* __restrict__ k16, const f16* __restrict__ v16,
                      const float* __restrict__ qs, const float* __restrict__ ks, const float* __restrict__ vs,
                      const float* __restrict__ nrope, const float* __restrict__ crope,
                      f16* __restrict__ qH, f16* __restrict__ kH, f16* __restrict__ vH) {
    const int r = blockIdx.x, h = blockIdx.y, d = threadIdx.x;
    const size_t src = (size_t)r * DIM_C + h * HD + d;
    float qv = (float)q16[src], kv = (float)k16[src], vv = (float)v16[src];
    float sq = qv * qv, sk = kv * kv, sv = vv * vv;
#pragma unroll
    for (int m = 1; m < 64; m <<= 1) {
        sq += __shfl_xor(sq, m);
        sk += __shfl_xor(sk, m);
        sv += __shfl_xor(sv, m);
    }
    __shared__ float part[3][2];
    const int wid = d >> 6;
    if ((d & 63) == 0) { part[0][wid] = sq; part[1][wid] = sk; part[2][wid] = sv; }
    __syncthreads();
    float rq = rsqrtf((part[0][0] + part[0][1]) * (1.0f / 128.0f) + 1e-6f);
    float rk = rsqrtf((part[1][0] + part[1][1]) * (1.0f / 128.0f) + 1e-6f);
    float rv = rsqrtf((part[2][0] + part[2][1]) * (1.0f / 128.0f) + 1e-6f);
    float qn = qv * rq * qs[d];
    float kn = kv * rk * ks[d];
    float vn = vv * rv * vs[d];
    __shared__ float shq[128], shk[128];
    shq[d] = qn; shk[d] = kn;
    __syncthreads();
    float rotq = (d < 64) ? -shq[d + 64] : shq[d - 64];
    float rotk = (d < 64) ? -shk[d + 64] : shk[d - 64];
    const float* rp = (r < L_NZ) ? (nrope + (size_t)r * HD) : (crope + (size_t)(r - L_NZ) * HD);
    float fr = rp[d];
    float c = cosf(fr), s = sinf(fr);
    const size_t dst = ((size_t)h * L_TOT + r) * HD + d;
    qH[dst] = (f16)((qn * c + rotq * s) * 0.08838834764831845f);  // 1/sqrt(128)
    kH[dst] = (f16)(kn * c + rotk * s);
    vH[dst] = (f16)vn;
}

// ---------------------------------------------------------------- flash attention v4
// 1D grid 384 blocks, XCD-clustered (xcd = bid&7 owns heads {xcd, xcd+8}); within each
// XCD the 16 SHORT cond blocks come first (rr 0..15) so they pair with long blocks on
// doubled CUs -> makespan 64 vs 96 iters. 4 waves x 32 queries, 64-key tiles, K double-
// buffered, counted-vmcnt pipeline (unchanged from v3).
// STATIC-MAX softmax: q,k are RMS-normed (scales=1) => |s| <= sqrt(128) = 11.32 by
// Cauchy-Schwarz. p = exp(s-4): max e^7.3=1510 (f16-safe), min e^-15.3=2.2e-7 (above f16
// subnormal-min => no zero rows). No max/sum shuffles, no rescale. Row-sum l accumulated
// in fp32 by an all-ones MFMA B-operand (exact softmax: shift-invariant, same f16 p in
// numerator and denominator).
__global__ __launch_bounds__(256, 2)
void flash_kernel(const f16* __restrict__ qH, const f16* __restrict__ kH,
                  const f16* __restrict__ vT, f16* __restrict__ xH) {
    __shared__ __align__(16) f16 lds_k[2][64 * 128];
    __shared__ __align__(16) f16 lds_v[64 * 128];
    __shared__ __align__(16) f16 p_lds[4][32][72];
    const int tid = threadIdx.x;
    const int lane = tid & 63, w = tid >> 6;
    const int bid = blockIdx.x;
    const int xcd = bid & 7, rr = bid >> 3;     // rr in [0,48)
    int h, qb;
    if (rr < 16) { h = xcd + 8 * (rr >> 3); qb = 16 + (rr & 7); }   // short (cond) first
    else         { int li = rr - 16; h = xcd + 8 * (li >> 4); qb = li & 15; } // long (noise)
    const int q0 = qb * 128 + w * 32;
    const int rl = lane & 15, rq = lane >> 4;

    // Q fragments (A operand): 2 q-tiles x 4 k-slices, loaded once from global
    half8 aq[2][4];
    const f16* qbase = qH + ((size_t)h * L_TOT + q0) * HD;
#pragma unroll
    for (int qt = 0; qt < 2; ++qt)
#pragma unroll
        for (int kc = 0; kc < 4; ++kc)
            aq[qt][kc] = *(const half8*)(qbase + (size_t)(qt * 16 + rl) * HD + kc * 32 + rq * 8);

    floatx4 acc[2][8] = {};
    floatx4 accl[2] = {};   // row-sum accumulator via ones-MFMA
    const half8 vone = {(f16)1.f, (f16)1.f, (f16)1.f, (f16)1.f,
                        (f16)1.f, (f16)1.f, (f16)1.f, (f16)1.f};

    const int kLo = (qb >= 16) ? L_NZ : 0;   // cond queries attend only cond keys
    const f16* khead = kH + (size_t)h * L_TOT * HD;
    const f16* vhead = vT + (size_t)h * HD * L_TOT;

    auto stageK = [&](int kb, int pb) {
#pragma unroll
        for (int is = 0; is < 4; ++is) {
            int i = is * 256 + tid;
            int r = i >> 4, c = i & 15;
            gl_lds16(khead + (size_t)(kb + r) * HD + ((c ^ (r & 15)) * 8),
                     &lds_k[pb][0] + (is * 256 + w * 64) * 8);
        }
    };
    auto stageV = [&](int kb) {
#pragma unroll
        for (int is = 0; is < 4; ++is) {
            int i = is * 256 + tid;
            int pair = i >> 4, c10 = i & 15;
            int g10 = c10 ^ (pair & 15);
            int d = pair * 2 + (g10 >> 3), kchunk = g10 & 7;
            gl_lds16(vhead + (size_t)d * L_TOT + kb + kchunk * 8,
                     lds_v + (is * 256 + w * 64) * 8);
        }
    };

    asm volatile("s_waitcnt vmcnt(0)" ::: "memory");   // drain Q loads -> deterministic counts
    stageK(kLo, 0);                                     // prefetch K(0); 4 issues in flight
    int p = 0;
    for (int kb = kLo; kb < L_TOT; kb += 64) {
        const int kbn = (kb + 64 < L_TOT) ? (kb + 64) : kLo;  // dummy refetch on last iter
        stageV(kb);                                     // +4 issues
        stageK(kbn, p ^ 1);                             // +4 issues
        asm volatile("s_waitcnt vmcnt(8)" ::: "memory");       // own K(kb) landed
        __builtin_amdgcn_s_barrier();                          // all waves' K(kb) landed
        __builtin_amdgcn_sched_barrier(0);

        // QK^T on lds_k[p]: sacc[qt][kf], keys kf*16+rl, q rows qt*16+(rq*4+j)
        const f16* kbase = &lds_k[p][0];
        floatx4 sacc[2][4] = {};
#pragma unroll
        for (int kf = 0; kf < 4; ++kf) {
            int r = kf * 16 + rl;
#pragma unroll
            for (int kc = 0; kc < 4; ++kc) {
                half8 bk = *(const half8*)(kbase + r * 128 + (((kc * 4 + rq) ^ (r & 15)) * 8));
                sacc[0][kf] = __builtin_amdgcn_mfma_f32_16x16x32_f16(aq[0][kc], bk, sacc[0][kf], 0, 0, 0);
                sacc[1][kf] = __builtin_amdgcn_mfma_f32_16x16x32_f16(aq[1][kc], bk, sacc[1][kf], 0, 0, 0);
            }
        }
        // static-max softmax: p = exp(s - 4), no reductions, no rescale
#pragma unroll
        for (int qt = 0; qt < 2; ++qt)
#pragma unroll
            for (int kf = 0; kf < 4; ++kf)
#pragma unroll
                for (int j = 0; j < 4; ++j) {
                    float pv = __expf(sacc[qt][kf][j] - 4.0f);
                    p_lds[w][qt * 16 + rq * 4 + j][kf * 16 + rl] = (f16)pv;
                }

        asm volatile("s_waitcnt vmcnt(4)" ::: "memory");       // own V(kb) landed (K(kbn) in flight)
        __builtin_amdgcn_s_barrier();                          // all waves' V(kb) landed
        __builtin_amdgcn_sched_barrier(0);

        // PV: A = P[32q][64k] via p_lds, B = V^T from lds_v; ones-column accumulates l
#pragma unroll
        for (int kc = 0; kc < 2; ++kc) {
            half8 ap0 = *(const half8*)(&p_lds[w][0 * 16 + rl][kc * 32 + rq * 8]);
            half8 ap1 = *(const half8*)(&p_lds[w][1 * 16 + rl][kc * 32 + rq * 8]);
            accl[0] = __builtin_amdgcn_mfma_f32_16x16x32_f16(ap0, vone, accl[0], 0, 0, 0);
            accl[1] = __builtin_amdgcn_mfma_f32_16x16x32_f16(ap1, vone, accl[1], 0, 0, 0);
#pragma unroll
            for (int dt = 0; dt < 8; ++dt) {
                int d = dt * 16 + rl;
                int g10 = (d & 1) * 8 + kc * 4 + rq;
                half8 bv = *(const half8*)(lds_v + (d >> 1) * 128 + ((g10 ^ ((d >> 1) & 15)) * 8));
                acc[0][dt] = __builtin_amdgcn_mfma_f32_16x16x32_f16(ap0, bv, acc[0][dt], 0, 0, 0);
                acc[1][dt] = __builtin_amdgcn_mfma_f32_16x16x32_f16(ap1, bv, acc[1][dt], 0, 0, 0);
            }
        }
        __builtin_amdgcn_s_barrier();     // all waves done reading lds_v before next stageV
        p ^= 1;
    }

    // epilogue: normalize by the ones-column row sum (all 16 cols identical; use own)
#pragma unroll
    for (int qt = 0; qt < 2; ++qt)
#pragma unroll
        for (int j = 0; j < 4; ++j) {
            float li = 1.0f / accl[qt][j];
            int row = q0 + qt * 16 + rq * 4 + j;
#pragma unroll
            for (int dt = 0; dt < 8; ++dt)
                xH[(size_t)row * DIM_C + h * HD + dt * 16 + rl] = (f16)(acc[qt][dt][j] * li);
        }
}

// ---------------------------------------------------------------- launch
extern "C" void kernel_launch(void* const* d_in, const int* in_sizes, int n_in,
                              void* d_out, int out_size, void* d_ws, size_t ws_size,
                              hipStream_t stream) {
    const float* noise = (const float*)d_in[0];
    const float* cond  = (const float*)d_in[1];
    const float* nrope = (const float*)d_in[2];
    const float* crope = (const float*)d_in[3];
    const float* Wq = (const float*)d_in[4];
    const float* Wk = (const float*)d_in[5];
    const float* Wv = (const float*)d_in[6];
    const float* Wo = (const float*)d_in[7];
    const float* bq = (const float*)d_in[8];
    const float* bk = (const float*)d_in[9];
    const float* bv = (const float*)d_in[10];
    const float* bo = (const float*)d_in[11];
    const float* qs = (const float*)d_in[12];
    const float* ks = (const float*)d_in[13];
    const float* vs = (const float*)d_in[14];
    const float* lqd = (const float*)d_in[15];
    const float* lqu = (const float*)d_in[16];
    const float* lkd = (const float*)d_in[17];
    const float* lku = (const float*)d_in[18];
    const float* lvd = (const float*)d_in[19];
    const float* lvu = (const float*)d_in[20];
    const float* lod = (const float*)d_in[21];
    const float* lou = (const float*)d_in[22];
    (void)in_sizes; (void)n_in; (void)out_size;

    char* ws = (char*)d_ws;
    const size_t SZ_LD = (size_t)L_TOT * DIM_C * sizeof(f16);   // 12.58 MB
    const size_t SZ_W  = (size_t)DIM_C * DIM_C * sizeof(f16);   //  8.39 MB
    size_t o = 0;
    auto take = [&](size_t b) { size_t r = o; o += (b + 255) & ~(size_t)255; return r; };
    f16* jointH   = (f16*)(ws + take(SZ_LD));
    f16* WTqkv    = (f16*)(ws + take(3 * SZ_W));
    f16* WT3      = (f16*)(ws + take(SZ_W));
    f16* downTqkv = (f16*)(ws + take((size_t)384 * 2048 * 2));
    f16* downTo   = (f16*)(ws + take((size_t)128 * 2048 * 2));
    f16* upT0     = (f16*)(ws + take((size_t)2048 * 128 * 2));
    f16* upT1     = (f16*)(ws + take((size_t)2048 * 128 * 2));
    f16* upT2     = (f16*)(ws + take((size_t)2048 * 128 * 2));
    f16* upTo     = (f16*)(ws + take((size_t)2048 * 128 * 2));
    f16* q16      = (f16*)(ws + take(3 * SZ_LD));   // q16,k16,v16 contiguous (SPLIT3)
    f16* k16      = q16 + (size_t)L_TOT * DIM_C;
    f16* v16      = k16 + (size_t)L_TOT * DIM_C;
    f16* t_all    = (f16*)(ws + take((size_t)1024 * 384 * 2));
    f16* t_o      = (f16*)(ws + take((size_t)1024 * 128 * 2));
    f16* qHd      = (f16*)(ws + take(SZ_LD));
    f16* kHd      = (f16*)(ws + take(SZ_LD));
    f16* vHd      = (f16*)(ws + take(SZ_LD));
    f16* vTd      = (f16*)(ws + take(SZ_LD));
    f16* xH       = (f16*)(ws + take(SZ_LD));
    if (o > ws_size) {
        sentinel_kernel<<<1, 1, 0, stream>>>((float*)d_out);
        return;
    }

    // 1) casts + weight transposes (B^T layout, f16)
    cast_f32_f16<<<dim3((2048 * 2048) / 1024), 256, 0, stream>>>(noise, jointH, 2048 * 2048);
    cast_f32_f16<<<dim3((1024 * 2048) / 1024), 256, 0, stream>>>(cond, jointH + (size_t)2048 * 2048, 1024 * 2048);
    transpose_cast<float><<<dim3(64, 64, 1), 256, 0, stream>>>(Wq, WTqkv,                          2048, 2048, 0, 0);
    transpose_cast<float><<<dim3(64, 64, 1), 256, 0, stream>>>(Wk, WTqkv + (size_t)2048 * 2048,     2048, 2048, 0, 0);
    transpose_cast<float><<<dim3(64, 64, 1), 256, 0, stream>>>(Wv, WTqkv + (size_t)2 * 2048 * 2048, 2048, 2048, 0, 0);
    transpose_cast<float><<<dim3(64, 64, 1), 256, 0, stream>>>(Wo, WT3, 2048, 2048, 0, 0);
    transpose_cast<float><<<dim3(4, 64, 1), 256, 0, stream>>>(lqd, downTqkv,                      2048, 128, 0, 0);
    transpose_cast<float><<<dim3(4, 64, 1), 256, 0, stream>>>(lkd, downTqkv + (size_t)128 * 2048, 2048, 128, 0, 0);
    transpose_cast<float><<<dim3(4, 64, 1), 256, 0, stream>>>(lvd, downTqkv + (size_t)256 * 2048, 2048, 128, 0, 0);
    transpose_cast<float><<<dim3(4, 64, 1), 256, 0, stream>>>(lod, downTo, 2048, 128, 0, 0);
    transpose_cast<float><<<dim3(64, 4, 1), 256, 0, stream>>>(lqu, upT0, 128, 2048, 0, 0);
    transpose_cast<float><<<dim3(64, 4, 1), 256, 0, stream>>>(lku, upT1, 128, 2048, 0, 0);
    transpose_cast<float><<<dim3(64, 4, 1), 256, 0, stream>>>(lvu, upT2, 128, 2048, 0, 0);
    transpose_cast<float><<<dim3(64, 4, 1), 256, 0, stream>>>(lou, upTo, 128, 2048, 0, 0);

    // 2) merged QKV projection (+per-chunk bias), then LoRA (cond rows only)
    gemm_tn<1, 0, 1, 1><<<dim3(6144 / 128, 3072 / 128), 256, 0, stream>>>(
        jointH, WTqkv, q16, bq, bk, bv, 3072, 6144, 2048, 2048, 2048, 2048, 1.0f);
    // stacked lora-down: t_all[1024][384] = joint_cond @ [Wdq|Wdk|Wdv]  (scale = 128/128 = 1)
    gemm_tn<1, 0, 0, 0><<<dim3(3, 8), 256, 0, stream>>>(jointH + (size_t)2048 * 2048, downTqkv, t_all,
                                                        nullptr, nullptr, nullptr,
                                                        1024, 384, 2048, 2048, 2048, 384, 1.0f);
    dim3 gup(2048 / 128, 1024 / 128);
    gemm_tn<1, 1, 0, 0><<<gup, 256, 0, stream>>>(t_all + 0,   upT0, q16 + (size_t)2048 * 2048,
                                                 nullptr, nullptr, nullptr, 1024, 2048, 128, 384, 128, 2048, 1.0f);
    gemm_tn<1, 1, 0, 0><<<gup, 256, 0, stream>>>(t_all + 128, upT1, k16 + (size_t)2048 * 2048,
                                                 nullptr, nullptr, nullptr, 1024, 2048, 128, 384, 128, 2048, 1.0f);
    gemm_tn<1, 1, 0, 0><<<gup, 256, 0, stream>>>(t_all + 256, upT2, v16 + (size_t)2048 * 2048,
                                                 nullptr, nullptr, nullptr, 1024, 2048, 128, 384, 128, 2048, 1.0f);

    // 3) RMS norm + RoPE -> head-major; transpose v per head
    norm_rope_kernel<<<dim3(3072, 16), 128, 0, stream>>>(q16, k16, v16, qs, ks, vs, nrope, crope, qHd, kHd, vHd);
    transpose_cast<f16><<<dim3(4, 96, 16), 256, 0, stream>>>(vHd, vTd, 3072, 128,
                                                             (long long)3072 * 128, (long long)128 * 3072);

    // 4) flash attention -> xH [L][2048]  (1D grid, XCD-clustered + load-balanced decode)
    flash_kernel<<<dim3(384), 256, 0, stream>>>(qHd, kHd, vTd, xH);

    // 5) output projection (+bias) and LoRA-o
    gemm_tn<0, 0, 1, 0><<<dim3(16, 24), 256, 0, stream>>>(xH, WT3, d_out, bo, nullptr, nullptr,
                                                          3072, 2048, 2048, 2048, 2048, 2048, 1.0f);
    gemm_tn<1, 0, 0, 0><<<dim3(1, 8), 256, 0, stream>>>(xH + (size_t)2048 * 2048, downTo, t_o,
                                                        nullptr, nullptr, nullptr,
                                                        1024, 128, 2048, 2048, 2048, 128, 1.0f);
    gemm_tn<0, 1, 0, 0><<<gup, 256, 0, stream>>>(t_o, upTo, (float*)d_out + (size_t)2048 * 2048,
                                                 nullptr, nullptr, nullptr,
                                                 1024, 2048, 128, 128, 128, 2048, 1.0f);
}

// Round 9
// 402.570 us; speedup vs baseline: 2.0320x; 1.1515x over previous
//
#include <hip/hip_runtime.h>

typedef _Float16 f16;
typedef _Float16 half8 __attribute__((ext_vector_type(8)));
typedef float floatx4 __attribute__((ext_vector_type(4)));

#define L_TOT   3072
#define L_NZ    2048
#define DIM_C   2048
#define NH      16
#define HD      128

// ---------------------------------------------------------------- helpers
__device__ __forceinline__ void gl_lds16(const f16* g, f16* l) {
    // async global->LDS, 16B per lane; LDS dest = wave-uniform base + lane*16
    __builtin_amdgcn_global_load_lds((__attribute__((address_space(1))) void*)g,
                                     (__attribute__((address_space(3))) void*)l,
                                     16, 0, 0);
}

__global__ void sentinel_kernel(float* out) { out[0] = 1.0e6f; }

// ---------------------------------------------------------------- cast f32 -> f16
__global__ __launch_bounds__(256)
void cast_f32_f16(const float* __restrict__ in, f16* __restrict__ out, int n) {
    int i = (blockIdx.x * 256 + threadIdx.x) * 4;
    if (i + 3 < n) {
        float4 v = *(const float4*)(in + i);
        out[i+0] = (f16)v.x; out[i+1] = (f16)v.y;
        out[i+2] = (f16)v.z; out[i+3] = (f16)v.w;
    }
}

// ---------------------------------------------------------------- transpose (+cast) -> f16, out[c][r] = in[r][c]
template<typename TIN>
__global__ __launch_bounds__(256)
void transpose_cast(const TIN* __restrict__ in, f16* __restrict__ out,
                    int R, int C, long long inBatch, long long outBatch) {
    in  += (long long)blockIdx.z * inBatch;
    out += (long long)blockIdx.z * outBatch;
    __shared__ f16 tile[32][33];
    int x = threadIdx.x & 31, y0 = threadIdx.x >> 5;
    int r0 = blockIdx.y * 32, c0 = blockIdx.x * 32;
#pragma unroll
    for (int i = 0; i < 4; ++i) {
        int y = y0 + i * 8;
        tile[y][x] = (f16)(float)in[(size_t)(r0 + y) * C + (c0 + x)];
    }
    __syncthreads();
#pragma unroll
    for (int i = 0; i < 4; ++i) {
        int y = y0 + i * 8;
        out[(size_t)(c0 + y) * R + (r0 + x)] = tile[x][y];
    }
}

// ---------------------------------------------------------------- GEMM v2: C[M][N] = A[M][K]*BT[N][K]^T (f16 in, f32 acc)
// 128x128 tile, BK=64 (rows 128B = 8 x 16B chunks), 4 waves 2x2, wave 64x64 via 4x4 frags.
// LDS XOR swizzle: position p of row r holds global chunk p^(r&7) (applied on the global
// source address; LDS dest linear for global_load_lds; read at chunk^(r&7)) -> each
// 16-lane read group covers all 8 slot positions = conflict-free ds_read_b128.
// Double-buffered with counted vmcnt(8): next tile's 8 staging loads stay in flight
// across compute (flash-v3-proven pattern). 2 barriers per 64-K step.
template<int WRITE_HALF, int ACCUM, int ADD_BIAS, int SPLIT3>
__global__ __launch_bounds__(256, 2)
void gemm_tn(const f16* __restrict__ A, const f16* __restrict__ BT,
             void* __restrict__ Cv,
             const float* __restrict__ bias0, const float* __restrict__ bias1,
             const float* __restrict__ bias2,
             int M, int N, int K, int lda, int ldb, int ldc, float cscale) {
    __shared__ __align__(16) f16 lds[2][2][128 * 64];   // [buf][A/B] 64 KB
    const int tid  = threadIdx.x;
    const int lane = tid & 63, wave = tid >> 6;
    const int m0 = blockIdx.y * 128, n0 = blockIdx.x * 128;
    const int wr = wave >> 1, wc = wave & 1;
    floatx4 acc[4][4] = {};

    // staging geometry: slot i = is*256+tid (16B each) -> row r=i>>3, pos c=i&7,
    // global chunk g = c^(r&7). r = is*32 + (tid>>3); c,g constant across is.
    const int r0i = tid >> 3;                       // 0..31
    const int gch = (tid & 7) ^ (r0i & 7);
    const f16* gA0 = A  + (size_t)(m0 + r0i) * lda + gch * 8;
    const f16* gB0 = BT + (size_t)(n0 + r0i) * ldb + gch * 8;
    const int ldsW = wave * 512;                    // wave-uniform base (f16 elems)

    auto stage = [&](int buf, int k0) {
#pragma unroll
        for (int is = 0; is < 4; ++is)
            gl_lds16(gA0 + k0 + (size_t)is * 32 * lda, &lds[buf][0][0] + is * 2048 + ldsW);
#pragma unroll
        for (int is = 0; is < 4; ++is)
            gl_lds16(gB0 + k0 + (size_t)is * 32 * ldb, &lds[buf][1][0] + is * 2048 + ldsW);
    };

    const int rl = lane & 15, cq = lane >> 4;       // frag row-in-16, chunk base

    const int nIter = K >> 6;
    stage(0, 0);                                    // prologue: 8 issues in flight
    int cur = 0;
    for (int t = 0; t < nIter; ++t) {
        const int k0n = (t + 1 < nIter) ? (t + 1) * 64 : 0;   // dummy refetch last iter
        stage(cur ^ 1, k0n);                        // +8 -> 16 in flight
        asm volatile("s_waitcnt vmcnt(8)" ::: "memory");      // own cur-tile landed
        __builtin_amdgcn_s_barrier();                         // all waves' cur landed
        __builtin_amdgcn_sched_barrier(0);

#pragma unroll
        for (int kh = 0; kh < 2; ++kh) {
            half8 af[4], bf[4];
#pragma unroll
            for (int m = 0; m < 4; ++m) {
                int row = wr * 64 + m * 16 + rl;
                int pos = (kh * 4 + cq) ^ (row & 7);
                af[m] = *(const half8*)(&lds[cur][0][row * 64 + pos * 8]);
            }
#pragma unroll
            for (int n = 0; n < 4; ++n) {
                int row = wc * 64 + n * 16 + rl;
                int pos = (kh * 4 + cq) ^ (row & 7);
                bf[n] = *(const half8*)(&lds[cur][1][row * 64 + pos * 8]);
            }
#pragma unroll
            for (int m = 0; m < 4; ++m)
#pragma unroll
                for (int n = 0; n < 4; ++n)
                    acc[m][n] = __builtin_amdgcn_mfma_f32_16x16x32_f16(af[m], bf[n], acc[m][n], 0, 0, 0);
        }
        __builtin_amdgcn_s_barrier();               // all waves done reading cur
        __builtin_amdgcn_sched_barrier(0);
        cur ^= 1;
    }

    // epilogue: C col = lane&15, row = (lane>>4)*4 + j
    const int rq = lane >> 4;
    const float* bias = bias0;
    size_t cbase = 0;
    if (SPLIT3) {
        int chunk = n0 >> 11;
        bias = (chunk == 0) ? bias0 : ((chunk == 1) ? bias1 : bias2);
        cbase = (size_t)chunk * ((size_t)L_TOT * DIM_C);
    }
#pragma unroll
    for (int m = 0; m < 4; ++m) {
        int row = m0 + wr * 64 + m * 16 + rq * 4;
#pragma unroll
        for (int n = 0; n < 4; ++n) {
            int col = n0 + wc * 64 + n * 16 + rl;
            float badd = ADD_BIAS ? bias[SPLIT3 ? (col & 2047) : col] : 0.0f;
            int ccol = SPLIT3 ? (col & 2047) : col;
#pragma unroll
            for (int j = 0; j < 4; ++j) {
                float v = acc[m][n][j] * cscale + badd;
                size_t idx = cbase + (size_t)(row + j) * ldc + ccol;
                if (WRITE_HALF) {
                    f16* C = (f16*)Cv;
                    if (ACCUM) v += (float)C[idx];
                    C[idx] = (f16)v;
                } else {
                    float* C = (float*)Cv;
                    if (ACCUM) v += C[idx];
                    C[idx] = v;
                }
            }
        }
    }
}

// ---------------------------------------------------------------- RMS norm + RoPE, writes head-major q/k (q pre-scaled 1/sqrt(128)) and v
__global__ __launch_bounds__(128)
void norm_rope_kernel(const f16* __restrict__ q16, const f16* __restrict__ k16, const f16* __restrict__ v16,
                      const float* __restrict__ qs, const float* __restrict__ ks, const float* __restrict__ vs,
                      const float* __restrict__ nrope, const float* __restrict__ crope,
                      f16* __restrict__ qH, f16* __restrict__ kH, f16* __restrict__ vH) {
    const int r = blockIdx.x, h = blockIdx.y, d = threadIdx.x;
    const size_t src = (size_t)r * DIM_C + h * HD + d;
    float qv = (float)q16[src], kv = (float)k16[src], vv = (float)v16[src];
    float sq = qv * qv, sk = kv * kv, sv = vv * vv;
#pragma unroll
    for (int m = 1; m < 64; m <<= 1) {
        sq += __shfl_xor(sq, m);
        sk += __shfl_xor(sk, m);
        sv += __shfl_xor(sv, m);
    }
    __shared__ float part[3][2];
    const int wid = d >> 6;
    if ((d & 63) == 0) { part[0][wid] = sq; part[1][wid] = sk; part[2][wid] = sv; }
    __syncthreads();
    float rq = rsqrtf((part[0][0] + part[0][1]) * (1.0f / 128.0f) + 1e-6f);
    float rk = rsqrtf((part[1][0] + part[1][1]) * (1.0f / 128.0f) + 1e-6f);
    float rv = rsqrtf((part[2][0] + part[2][1]) * (1.0f / 128.0f) + 1e-6f);
    float qn = qv * rq * qs[d];
    float kn = kv * rk * ks[d];
    float vn = vv * rv * vs[d];
    __shared__ float shq[128], shk[128];
    shq[d] = qn; shk[d] = kn;
    __syncthreads();
    float rotq = (d < 64) ? -shq[d + 64] : shq[d - 64];
    float rotk = (d < 64) ? -shk[d + 64] : shk[d - 64];
    const float* rp = (r < L_NZ) ? (nrope + (size_t)r * HD) : (crope + (size_t)(r - L_NZ) * HD);
    float fr = rp[d];
    float c = cosf(fr), s = sinf(fr);
    const size_t dst = ((size_t)h * L_TOT + r) * HD + d;
    qH[dst] = (f16)((qn * c + rotq * s) * 0.08838834764831845f);  // 1/sqrt(128)
    kH[dst] = (f16)(kn * c + rotk * s);
    vH[dst] = (f16)vn;
}

// ---------------------------------------------------------------- flash attention v4 (unchanged from round 7)
__global__ __launch_bounds__(256, 2)
void flash_kernel(const f16* __restrict__ qH, const f16* __restrict__ kH,
                  const f16* __restrict__ vT, f16* __restrict__ xH) {
    __shared__ __align__(16) f16 lds_k[2][64 * 128];
    __shared__ __align__(16) f16 lds_v[64 * 128];
    __shared__ __align__(16) f16 p_lds[4][32][72];
    const int tid = threadIdx.x;
    const int lane = tid & 63, w = tid >> 6;
    const int bid = blockIdx.x;
    const int xcd = bid & 7, rr = bid >> 3;     // rr in [0,48)
    int h, qb;
    if (rr < 16) { h = xcd + 8 * (rr >> 3); qb = 16 + (rr & 7); }   // short (cond) first
    else         { int li = rr - 16; h = xcd + 8 * (li >> 4); qb = li & 15; } // long (noise)
    const int q0 = qb * 128 + w * 32;
    const int rl = lane & 15, rq = lane >> 4;

    half8 aq[2][4];
    const f16* qbase = qH + ((size_t)h * L_TOT + q0) * HD;
#pragma unroll
    for (int qt = 0; qt < 2; ++qt)
#pragma unroll
        for (int kc = 0; kc < 4; ++kc)
            aq[qt][kc] = *(const half8*)(qbase + (size_t)(qt * 16 + rl) * HD + kc * 32 + rq * 8);

    floatx4 acc[2][8] = {};
    floatx4 accl[2] = {};   // row-sum accumulator via ones-MFMA
    const half8 vone = {(f16)1.f, (f16)1.f, (f16)1.f, (f16)1.f,
                        (f16)1.f, (f16)1.f, (f16)1.f, (f16)1.f};

    const int kLo = (qb >= 16) ? L_NZ : 0;   // cond queries attend only cond keys
    const f16* khead = kH + (size_t)h * L_TOT * HD;
    const f16* vhead = vT + (size_t)h * HD * L_TOT;

    auto stageK = [&](int kb, int pb) {
#pragma unroll
        for (int is = 0; is < 4; ++is) {
            int i = is * 256 + tid;
            int r = i >> 4, c = i & 15;
            gl_lds16(khead + (size_t)(kb + r) * HD + ((c ^ (r & 15)) * 8),
                     &lds_k[pb][0] + (is * 256 + w * 64) * 8);
        }
    };
    auto stageV = [&](int kb) {
#pragma unroll
        for (int is = 0; is < 4; ++is) {
            int i = is * 256 + tid;
            int pair = i >> 4, c10 = i & 15;
            int g10 = c10 ^ (pair & 15);
            int d = pair * 2 + (g10 >> 3), kchunk = g10 & 7;
            gl_lds16(vhead + (size_t)d * L_TOT + kb + kchunk * 8,
                     lds_v + (is * 256 + w * 64) * 8);
        }
    };

    asm volatile("s_waitcnt vmcnt(0)" ::: "memory");   // drain Q loads -> deterministic counts
    stageK(kLo, 0);                                     // prefetch K(0); 4 issues in flight
    int p = 0;
    for (int kb = kLo; kb < L_TOT; kb += 64) {
        const int kbn = (kb + 64 < L_TOT) ? (kb + 64) : kLo;  // dummy refetch on last iter
        stageV(kb);                                     // +4 issues
        stageK(kbn, p ^ 1);                             // +4 issues
        asm volatile("s_waitcnt vmcnt(8)" ::: "memory");       // own K(kb) landed
        __builtin_amdgcn_s_barrier();                          // all waves' K(kb) landed
        __builtin_amdgcn_sched_barrier(0);

        // QK^T on lds_k[p]: sacc[qt][kf], keys kf*16+rl, q rows qt*16+(rq*4+j)
        const f16* kbase = &lds_k[p][0];
        floatx4 sacc[2][4] = {};
#pragma unroll
        for (int kf = 0; kf < 4; ++kf) {
            int r = kf * 16 + rl;
#pragma unroll
            for (int kc = 0; kc < 4; ++kc) {
                half8 bk = *(const half8*)(kbase + r * 128 + (((kc * 4 + rq) ^ (r & 15)) * 8));
                sacc[0][kf] = __builtin_amdgcn_mfma_f32_16x16x32_f16(aq[0][kc], bk, sacc[0][kf], 0, 0, 0);
                sacc[1][kf] = __builtin_amdgcn_mfma_f32_16x16x32_f16(aq[1][kc], bk, sacc[1][kf], 0, 0, 0);
            }
        }
        // static-max softmax: p = exp(s - 4), no reductions, no rescale
#pragma unroll
        for (int qt = 0; qt < 2; ++qt)
#pragma unroll
            for (int kf = 0; kf < 4; ++kf)
#pragma unroll
                for (int j = 0; j < 4; ++j) {
                    float pv = __expf(sacc[qt][kf][j] - 4.0f);
                    p_lds[w][qt * 16 + rq * 4 + j][kf * 16 + rl] = (f16)pv;
                }

        asm volatile("s_waitcnt vmcnt(4)" ::: "memory");       // own V(kb) landed (K(kbn) in flight)
        __builtin_amdgcn_s_barrier();                          // all waves' V(kb) landed
        __builtin_amdgcn_sched_barrier(0);

        // PV: A = P[32q][64k] via p_lds, B = V^T from lds_v; ones-column accumulates l
#pragma unroll
        for (int kc = 0; kc < 2; ++kc) {
            half8 ap0 = *(const half8*)(&p_lds[w][0 * 16 + rl][kc * 32 + rq * 8]);
            half8 ap1 = *(const half8*)(&p_lds[w][1 * 16 + rl][kc * 32 + rq * 8]);
            accl[0] = __builtin_amdgcn_mfma_f32_16x16x32_f16(ap0, vone, accl[0], 0, 0, 0);
            accl[1] = __builtin_amdgcn_mfma_f32_16x16x32_f16(ap1, vone, accl[1], 0, 0, 0);
#pragma unroll
            for (int dt = 0; dt < 8; ++dt) {
                int d = dt * 16 + rl;
                int g10 = (d & 1) * 8 + kc * 4 + rq;
                half8 bv = *(const half8*)(lds_v + (d >> 1) * 128 + ((g10 ^ ((d >> 1) & 15)) * 8));
                acc[0][dt] = __builtin_amdgcn_mfma_f32_16x16x32_f16(ap0, bv, acc[0][dt], 0, 0, 0);
                acc[1][dt] = __builtin_amdgcn_mfma_f32_16x16x32_f16(ap1, bv, acc[1][dt], 0, 0, 0);
            }
        }
        __builtin_amdgcn_s_barrier();     // all waves done reading lds_v before next stageV
        p ^= 1;
    }

    // epilogue: normalize by the ones-column row sum
#pragma unroll
    for (int qt = 0; qt < 2; ++qt)
#pragma unroll
        for (int j = 0; j < 4; ++j) {
            float li = 1.0f / accl[qt][j];
            int row = q0 + qt * 16 + rq * 4 + j;
#pragma unroll
            for (int dt = 0; dt < 8; ++dt)
                xH[(size_t)row * DIM_C + h * HD + dt * 16 + rl] = (f16)(acc[qt][dt][j] * li);
        }
}

// ---------------------------------------------------------------- launch
extern "C" void kernel_launch(void* const* d_in, const int* in_sizes, int n_in,
                              void* d_out, int out_size, void* d_ws, size_t ws_size,
                              hipStream_t stream) {
    const float* noise = (const float*)d_in[0];
    const float* cond  = (const float*)d_in[1];
    const float* nrope = (const float*)d_in[2];
    const float* crope = (const float*)d_in[3];
    const float* Wq = (const float*)d_in[4];
    const float* Wk = (const float*)d_in[5];
    const float* Wv = (const float*)d_in[6];
    const float* Wo = (const float*)d_in[7];
    const float* bq = (const float*)d_in[8];
    const float* bk = (const float*)d_in[9];
    const float* bv = (const float*)d_in[10];
    const float* bo = (const float*)d_in[11];
    const float* qs = (const float*)d_in[12];
    const float* ks = (const float*)d_in[13];
    const float* vs = (const float*)d_in[14];
    const float* lqd = (const float*)d_in[15];
    const float* lqu = (const float*)d_in[16];
    const float* lkd = (const float*)d_in[17];
    const float* lku = (const float*)d_in[18];
    const float* lvd = (const float*)d_in[19];
    const float* lvu = (const float*)d_in[20];
    const float* lod = (const float*)d_in[21];
    const float* lou = (const float*)d_in[22];
    (void)in_sizes; (void)n_in; (void)out_size;

    char* ws = (char*)d_ws;
    const size_t SZ_LD = (size_t)L_TOT * DIM_C * sizeof(f16);   // 12.58 MB
    const size_t SZ_W  = (size_t)DIM_C * DIM_C * sizeof(f16);   //  8.39 MB
    size_t o = 0;
    auto take = [&](size_t b) { size_t r = o; o += (b + 255) & ~(size_t)255; return r; };
    f16* jointH   = (f16*)(ws + take(SZ_LD));
    f16* WTqkv    = (f16*)(ws + take(3 * SZ_W));
    f16* WT3      = (f16*)(ws + take(SZ_W));
    f16* downTqkv = (f16*)(ws + take((size_t)384 * 2048 * 2));
    f16* downTo   = (f16*)(ws + take((size_t)128 * 2048 * 2));
    f16* upT0     = (f16*)(ws + take((size_t)2048 * 128 * 2));
    f16* upT1     = (f16*)(ws + take((size_t)2048 * 128 * 2));
    f16* upT2     = (f16*)(ws + take((size_t)2048 * 128 * 2));
    f16* upTo     = (f16*)(ws + take((size_t)2048 * 128 * 2));
    f16* q16      = (f16*)(ws + take(3 * SZ_LD));   // q16,k16,v16 contiguous (SPLIT3)
    f16* k16      = q16 + (size_t)L_TOT * DIM_C;
    f16* v16      = k16 + (size_t)L_TOT * DIM_C;
    f16* t_all    = (f16*)(ws + take((size_t)1024 * 384 * 2));
    f16* t_o      = (f16*)(ws + take((size_t)1024 * 128 * 2));
    f16* qHd      = (f16*)(ws + take(SZ_LD));
    f16* kHd      = (f16*)(ws + take(SZ_LD));
    f16* vHd      = (f16*)(ws + take(SZ_LD));
    f16* vTd      = (f16*)(ws + take(SZ_LD));
    f16* xH       = (f16*)(ws + take(SZ_LD));
    if (o > ws_size) {
        sentinel_kernel<<<1, 1, 0, stream>>>((float*)d_out);
        return;
    }

    // 1) casts + weight transposes (B^T layout, f16)
    cast_f32_f16<<<dim3((2048 * 2048) / 1024), 256, 0, stream>>>(noise, jointH, 2048 * 2048);
    cast_f32_f16<<<dim3((1024 * 2048) / 1024), 256, 0, stream>>>(cond, jointH + (size_t)2048 * 2048, 1024 * 2048);
    transpose_cast<float><<<dim3(64, 64, 1), 256, 0, stream>>>(Wq, WTqkv,                          2048, 2048, 0, 0);
    transpose_cast<float><<<dim3(64, 64, 1), 256, 0, stream>>>(Wk, WTqkv + (size_t)2048 * 2048,     2048, 2048, 0, 0);
    transpose_cast<float><<<dim3(64, 64, 1), 256, 0, stream>>>(Wv, WTqkv + (size_t)2 * 2048 * 2048, 2048, 2048, 0, 0);
    transpose_cast<float><<<dim3(64, 64, 1), 256, 0, stream>>>(Wo, WT3, 2048, 2048, 0, 0);
    transpose_cast<float><<<dim3(4, 64, 1), 256, 0, stream>>>(lqd, downTqkv,                      2048, 128, 0, 0);
    transpose_cast<float><<<dim3(4, 64, 1), 256, 0, stream>>>(lkd, downTqkv + (size_t)128 * 2048, 2048, 128, 0, 0);
    transpose_cast<float><<<dim3(4, 64, 1), 256, 0, stream>>>(lvd, downTqkv + (size_t)256 * 2048, 2048, 128, 0, 0);
    transpose_cast<float><<<dim3(4, 64, 1), 256, 0, stream>>>(lod, downTo, 2048, 128, 0, 0);
    transpose_cast<float><<<dim3(64, 4, 1), 256, 0, stream>>>(lqu, upT0, 128, 2048, 0, 0);
    transpose_cast<float><<<dim3(64, 4, 1), 256, 0, stream>>>(lku, upT1, 128, 2048, 0, 0);
    transpose_cast<float><<<dim3(64, 4, 1), 256, 0, stream>>>(lvu, upT2, 128, 2048, 0, 0);
    transpose_cast<float><<<dim3(64, 4, 1), 256, 0, stream>>>(lou, upTo, 128, 2048, 0, 0);

    // 2) merged QKV projection (+per-chunk bias), then LoRA (cond rows only)
    gemm_tn<1, 0, 1, 1><<<dim3(6144 / 128, 3072 / 128), 256, 0, stream>>>(
        jointH, WTqkv, q16, bq, bk, bv, 3072, 6144, 2048, 2048, 2048, 2048, 1.0f);
    // stacked lora-down: t_all[1024][384] = joint_cond @ [Wdq|Wdk|Wdv]  (scale = 128/128 = 1)
    gemm_tn<1, 0, 0, 0><<<dim3(3, 8), 256, 0, stream>>>(jointH + (size_t)2048 * 2048, downTqkv, t_all,
                                                        nullptr, nullptr, nullptr,
                                                        1024, 384, 2048, 2048, 2048, 384, 1.0f);
    dim3 gup(2048 / 128, 1024 / 128);
    gemm_tn<1, 1, 0, 0><<<gup, 256, 0, stream>>>(t_all + 0,   upT0, q16 + (size_t)2048 * 2048,
                                                 nullptr, nullptr, nullptr, 1024, 2048, 128, 384, 128, 2048, 1.0f);
    gemm_tn<1, 1, 0, 0><<<gup, 256, 0, stream>>>(t_all + 128, upT1, k16 + (size_t)2048 * 2048,
                                                 nullptr, nullptr, nullptr, 1024, 2048, 128, 384, 128, 2048, 1.0f);
    gemm_tn<1, 1, 0, 0><<<gup, 256, 0, stream>>>(t_all + 256, upT2, v16 + (size_t)2048 * 2048,
                                                 nullptr, nullptr, nullptr, 1024, 2048, 128, 384, 128, 2048, 1.0f);

    // 3) RMS norm + RoPE -> head-major; transpose v per head
    norm_rope_kernel<<<dim3(3072, 16), 128, 0, stream>>>(q16, k16, v16, qs, ks, vs, nrope, crope, qHd, kHd, vHd);
    transpose_cast<f16><<<dim3(4, 96, 16), 256, 0, stream>>>(vHd, vTd, 3072, 128,
                                                             (long long)3072 * 128, (long long)128 * 3072);

    // 4) flash attention -> xH [L][2048]  (1D grid, XCD-clustered + load-balanced decode)
    flash_kernel<<<dim3(384), 256, 0, stream>>>(qHd, kHd, vTd, xH);

    // 5) output projection (+bias) and LoRA-o
    gemm_tn<0, 0, 1, 0><<<dim3(16, 24), 256, 0, stream>>>(xH, WT3, d_out, bo, nullptr, nullptr,
                                                          3072, 2048, 2048, 2048, 2048, 2048, 1.0f);
    gemm_tn<1, 0, 0, 0><<<dim3(1, 8), 256, 0, stream>>>(xH + (size_t)2048 * 2048, downTo, t_o,
                                                        nullptr, nullptr, nullptr,
                                                        1024, 128, 2048, 2048, 2048, 128, 1.0f);
    gemm_tn<0, 1, 0, 0><<<gup, 256, 0, stream>>>(t_o, upTo, (float*)d_out + (size_t)2048 * 2048,
                                                 nullptr, nullptr, nullptr,
                                                 1024, 2048, 128, 128, 128, 2048, 1.0f);
}

// Round 10
// 355.595 us; speedup vs baseline: 2.3004x; 1.1321x over previous
//
#include <hip/hip_runtime.h>

typedef _Float16 f16;
typedef _Float16 half8 __attribute__((ext_vector_type(8)));
typedef float floatx4 __attribute__((ext_vector_type(4)));

#define L_TOT   3072
#define L_NZ    2048
#define DIM_C   2048
#define NH      16
#define HD      128

// ---------------------------------------------------------------- helpers
__device__ __forceinline__ void gl_lds16(const f16* g, f16* l) {
    __builtin_amdgcn_global_load_lds((__attribute__((address_space(1))) void*)g,
                                     (__attribute__((address_space(3))) void*)l,
                                     16, 0, 0);
}

__global__ void sentinel_kernel(float* out) { out[0] = 1.0e6f; }

// ---------------------------------------------------------------- fused cast: joint = [noise;cond] f32 -> f16
__global__ __launch_bounds__(256)
void cast_joint(const float* __restrict__ noise, const float* __restrict__ cond,
                f16* __restrict__ out) {
    int i = (blockIdx.x * 256 + threadIdx.x) * 4;      // grid covers 3072*2048
    const float* src; int off;
    if (i < 2048 * 2048) { src = noise; off = i; }
    else                 { src = cond;  off = i - 2048 * 2048; }
    float4 v = *(const float4*)(src + off);
    out[i+0] = (f16)v.x; out[i+1] = (f16)v.y;
    out[i+2] = (f16)v.z; out[i+3] = (f16)v.w;
}

// ---------------------------------------------------------------- batched transpose(+cast): out[z][c][r] = in_z[r][c]
__global__ __launch_bounds__(256)
void transpose_cast4(const float* __restrict__ s0, const float* __restrict__ s1,
                     const float* __restrict__ s2, const float* __restrict__ s3,
                     f16* __restrict__ dstBase, int R, int C, long long outBatch) {
    const float* in = (blockIdx.z == 0) ? s0 : (blockIdx.z == 1) ? s1 : (blockIdx.z == 2) ? s2 : s3;
    f16* out = dstBase + (long long)blockIdx.z * outBatch;
    __shared__ f16 tile[32][33];
    int x = threadIdx.x & 31, y0 = threadIdx.x >> 5;
    int r0 = blockIdx.y * 32, c0 = blockIdx.x * 32;
#pragma unroll
    for (int i = 0; i < 4; ++i) {
        int y = y0 + i * 8;
        tile[y][x] = (f16)in[(size_t)(r0 + y) * C + (c0 + x)];
    }
    __syncthreads();
#pragma unroll
    for (int i = 0; i < 4; ++i) {
        int y = y0 + i * 8;
        out[(size_t)(c0 + y) * R + (r0 + x)] = tile[x][y];
    }
}

// ---------------------------------------------------------------- GEMM v2: C[M][N] = A[M][K]*BT[N][K]^T (f16 in, f32 acc)
// 128x128 tile, BK=64, XOR-swizzled LDS (global-source side), double-buffered counted vmcnt(8).
// MODE 0: plain. MODE 1: QKV split (per-2048-chunk bias + C base). MODE 2: lora-up merged
// (A += chunk*128 into t_all, per-chunk C base, no bias).
template<int WRITE_HALF, int ACCUM, int ADD_BIAS, int MODE>
__global__ __launch_bounds__(256, 2)
void gemm_tn(const f16* __restrict__ A, const f16* __restrict__ BT,
             void* __restrict__ Cv,
             const float* __restrict__ bias0, const float* __restrict__ bias1,
             const float* __restrict__ bias2,
             int M, int N, int K, int lda, int ldb, int ldc, float cscale) {
    __shared__ __align__(16) f16 lds[2][2][128 * 64];   // [buf][A/B] 64 KB
    const int tid  = threadIdx.x;
    const int lane = tid & 63, wave = tid >> 6;
    const int m0 = blockIdx.y * 128, n0 = blockIdx.x * 128;
    const int wr = wave >> 1, wc = wave & 1;
    floatx4 acc[4][4] = {};

    if (MODE == 2) A += (size_t)(n0 >> 11) * 128;

    const int r0i = tid >> 3;                       // 0..31
    const int gch = (tid & 7) ^ (r0i & 7);
    const f16* gA0 = A  + (size_t)(m0 + r0i) * lda + gch * 8;
    const f16* gB0 = BT + (size_t)(n0 + r0i) * ldb + gch * 8;
    const int ldsW = wave * 512;

    auto stage = [&](int buf, int k0) {
#pragma unroll
        for (int is = 0; is < 4; ++is)
            gl_lds16(gA0 + k0 + (size_t)is * 32 * lda, &lds[buf][0][0] + is * 2048 + ldsW);
#pragma unroll
        for (int is = 0; is < 4; ++is)
            gl_lds16(gB0 + k0 + (size_t)is * 32 * ldb, &lds[buf][1][0] + is * 2048 + ldsW);
    };

    const int rl = lane & 15, cq = lane >> 4;

    const int nIter = K >> 6;
    stage(0, 0);
    int cur = 0;
    for (int t = 0; t < nIter; ++t) {
        const int k0n = (t + 1 < nIter) ? (t + 1) * 64 : 0;
        stage(cur ^ 1, k0n);
        asm volatile("s_waitcnt vmcnt(8)" ::: "memory");
        __builtin_amdgcn_s_barrier();
        __builtin_amdgcn_sched_barrier(0);

#pragma unroll
        for (int kh = 0; kh < 2; ++kh) {
            half8 af[4], bf[4];
#pragma unroll
            for (int m = 0; m < 4; ++m) {
                int row = wr * 64 + m * 16 + rl;
                int pos = (kh * 4 + cq) ^ (row & 7);
                af[m] = *(const half8*)(&lds[cur][0][row * 64 + pos * 8]);
            }
#pragma unroll
            for (int n = 0; n < 4; ++n) {
                int row = wc * 64 + n * 16 + rl;
                int pos = (kh * 4 + cq) ^ (row & 7);
                bf[n] = *(const half8*)(&lds[cur][1][row * 64 + pos * 8]);
            }
#pragma unroll
            for (int m = 0; m < 4; ++m)
#pragma unroll
                for (int n = 0; n < 4; ++n)
                    acc[m][n] = __builtin_amdgcn_mfma_f32_16x16x32_f16(af[m], bf[n], acc[m][n], 0, 0, 0);
        }
        __builtin_amdgcn_s_barrier();
        __builtin_amdgcn_sched_barrier(0);
        cur ^= 1;
    }

    // epilogue: C col = lane&15, row = (lane>>4)*4 + j
    const int rq = lane >> 4;
    const float* bias = bias0;
    size_t cbase = 0;
    if (MODE == 1 || MODE == 2) {
        int chunk = n0 >> 11;
        if (MODE == 1) bias = (chunk == 0) ? bias0 : ((chunk == 1) ? bias1 : bias2);
        cbase = (size_t)chunk * ((size_t)L_TOT * DIM_C);
    }
#pragma unroll
    for (int m = 0; m < 4; ++m) {
        int row = m0 + wr * 64 + m * 16 + rq * 4;
#pragma unroll
        for (int n = 0; n < 4; ++n) {
            int col = n0 + wc * 64 + n * 16 + rl;
            int ccol = (MODE == 1 || MODE == 2) ? (col & 2047) : col;
            float badd = ADD_BIAS ? bias[ccol] : 0.0f;
#pragma unroll
            for (int j = 0; j < 4; ++j) {
                float v = acc[m][n][j] * cscale + badd;
                size_t idx = cbase + (size_t)(row + j) * ldc + ccol;
                if (WRITE_HALF) {
                    f16* C = (f16*)Cv;
                    if (ACCUM) v += (float)C[idx];
                    C[idx] = (f16)v;
                } else {
                    float* C = (float*)Cv;
                    if (ACCUM) v += C[idx];
                    C[idx] = v;
                }
            }
        }
    }
}

// ---------------------------------------------------------------- fused RMS norm + RoPE + V-transpose
// grid (96, 16), 256 thr. Block = 32 rows x one head. Thread (rloc=t>>3, c=t&7) owns
// d in {c*8..c*8+7} U {64+c*8..}: rotate-half pairs are in-thread. fr[d+64]==fr[d]
// (concat construction) -> one cos/sin per low-half element. V is normalized then
// transposed via an LDS tile into vT[h][d][r].
__global__ __launch_bounds__(256)
void norm_rope_v(const f16* __restrict__ q16, const f16* __restrict__ k16, const f16* __restrict__ v16,
                 const float* __restrict__ qs, const float* __restrict__ ks, const float* __restrict__ vs,
                 const float* __restrict__ nrope, const float* __restrict__ crope,
                 f16* __restrict__ qH, f16* __restrict__ kH, f16* __restrict__ vT) {
    __shared__ f16 vtile[128][33];
    const int t = threadIdx.x, rloc = t >> 3, c = t & 7;
    const int r = blockIdx.x * 32 + rloc, h = blockIdx.y;
    const int d0 = c * 8;
    const size_t src = (size_t)r * DIM_C + h * HD;
    half8 qlv = *(const half8*)(q16 + src + d0);
    half8 qhv = *(const half8*)(q16 + src + 64 + d0);
    half8 klv = *(const half8*)(k16 + src + d0);
    half8 khv = *(const half8*)(k16 + src + 64 + d0);
    half8 vlv = *(const half8*)(v16 + src + d0);
    half8 vhv = *(const half8*)(v16 + src + 64 + d0);
    float ql[8], qh[8], kl[8], kh[8], vl[8], vh[8];
    float sq = 0.f, sk = 0.f, sv = 0.f;
#pragma unroll
    for (int i = 0; i < 8; ++i) {
        ql[i] = (float)qlv[i]; qh[i] = (float)qhv[i];
        kl[i] = (float)klv[i]; kh[i] = (float)khv[i];
        vl[i] = (float)vlv[i]; vh[i] = (float)vhv[i];
        sq += ql[i]*ql[i] + qh[i]*qh[i];
        sk += kl[i]*kl[i] + kh[i]*kh[i];
        sv += vl[i]*vl[i] + vh[i]*vh[i];
    }
    sq += __shfl_xor(sq, 1); sq += __shfl_xor(sq, 2); sq += __shfl_xor(sq, 4);
    sk += __shfl_xor(sk, 1); sk += __shfl_xor(sk, 2); sk += __shfl_xor(sk, 4);
    sv += __shfl_xor(sv, 1); sv += __shfl_xor(sv, 2); sv += __shfl_xor(sv, 4);
    const float rqs = rsqrtf(sq * (1.0f / 128.0f) + 1e-6f);
    const float rks = rsqrtf(sk * (1.0f / 128.0f) + 1e-6f);
    const float rvs = rsqrtf(sv * (1.0f / 128.0f) + 1e-6f);
    const float* rp = (r < L_NZ) ? (nrope + (size_t)r * HD) : (crope + (size_t)(r - L_NZ) * HD);
    half8 qo_l, qo_h, ko_l, ko_h;
#pragma unroll
    for (int i = 0; i < 8; ++i) {
        float fr = rp[d0 + i];
        float cs = cosf(fr), sn = sinf(fr);
        float qnl = ql[i] * rqs * qs[d0 + i],      qnh = qh[i] * rqs * qs[64 + d0 + i];
        float knl = kl[i] * rks * ks[d0 + i],      knh = kh[i] * rks * ks[64 + d0 + i];
        qo_l[i] = (f16)((qnl * cs - qnh * sn) * 0.08838834764831845f);
        qo_h[i] = (f16)((qnh * cs + qnl * sn) * 0.08838834764831845f);
        ko_l[i] = (f16)(knl * cs - knh * sn);
        ko_h[i] = (f16)(knh * cs + knl * sn);
        vtile[d0 + i][rloc]      = (f16)(vl[i] * rvs * vs[d0 + i]);
        vtile[64 + d0 + i][rloc] = (f16)(vh[i] * rvs * vs[64 + d0 + i]);
    }
    const size_t dst = ((size_t)h * L_TOT + r) * HD;
    *(half8*)(qH + dst + d0) = qo_l;      *(half8*)(qH + dst + 64 + d0) = qo_h;
    *(half8*)(kH + dst + d0) = ko_l;      *(half8*)(kH + dst + 64 + d0) = ko_h;
    __syncthreads();
    const int dd = t >> 1, seg = (t & 1) * 16;
    half8 o0, o1;
#pragma unroll
    for (int i = 0; i < 8; ++i) { o0[i] = vtile[dd][seg + i]; o1[i] = vtile[dd][seg + 8 + i]; }
    f16* vdst = vT + ((size_t)h * HD + dd) * L_TOT + blockIdx.x * 32 + seg;
    *(half8*)(vdst)     = o0;
    *(half8*)(vdst + 8) = o1;
}

// ---------------------------------------------------------------- flash attention v4 + setprio (T5)
__global__ __launch_bounds__(256, 2)
void flash_kernel(const f16* __restrict__ qH, const f16* __restrict__ kH,
                  const f16* __restrict__ vT, f16* __restrict__ xH) {
    __shared__ __align__(16) f16 lds_k[2][64 * 128];
    __shared__ __align__(16) f16 lds_v[64 * 128];
    __shared__ __align__(16) f16 p_lds[4][32][72];
    const int tid = threadIdx.x;
    const int lane = tid & 63, w = tid >> 6;
    const int bid = blockIdx.x;
    const int xcd = bid & 7, rr = bid >> 3;
    int h, qb;
    if (rr < 16) { h = xcd + 8 * (rr >> 3); qb = 16 + (rr & 7); }
    else         { int li = rr - 16; h = xcd + 8 * (li >> 4); qb = li & 15; }
    const int q0 = qb * 128 + w * 32;
    const int rl = lane & 15, rq = lane >> 4;

    half8 aq[2][4];
    const f16* qbase = qH + ((size_t)h * L_TOT + q0) * HD;
#pragma unroll
    for (int qt = 0; qt < 2; ++qt)
#pragma unroll
        for (int kc = 0; kc < 4; ++kc)
            aq[qt][kc] = *(const half8*)(qbase + (size_t)(qt * 16 + rl) * HD + kc * 32 + rq * 8);

    floatx4 acc[2][8] = {};
    floatx4 accl[2] = {};
    const half8 vone = {(f16)1.f, (f16)1.f, (f16)1.f, (f16)1.f,
                        (f16)1.f, (f16)1.f, (f16)1.f, (f16)1.f};

    const int kLo = (qb >= 16) ? L_NZ : 0;
    const f16* khead = kH + (size_t)h * L_TOT * HD;
    const f16* vhead = vT + (size_t)h * HD * L_TOT;

    auto stageK = [&](int kb, int pb) {
#pragma unroll
        for (int is = 0; is < 4; ++is) {
            int i = is * 256 + tid;
            int r = i >> 4, c = i & 15;
            gl_lds16(khead + (size_t)(kb + r) * HD + ((c ^ (r & 15)) * 8),
                     &lds_k[pb][0] + (is * 256 + w * 64) * 8);
        }
    };
    auto stageV = [&](int kb) {
#pragma unroll
        for (int is = 0; is < 4; ++is) {
            int i = is * 256 + tid;
            int pair = i >> 4, c10 = i & 15;
            int g10 = c10 ^ (pair & 15);
            int d = pair * 2 + (g10 >> 3), kchunk = g10 & 7;
            gl_lds16(vhead + (size_t)d * L_TOT + kb + kchunk * 8,
                     lds_v + (is * 256 + w * 64) * 8);
        }
    };

    asm volatile("s_waitcnt vmcnt(0)" ::: "memory");
    stageK(kLo, 0);
    int p = 0;
    for (int kb = kLo; kb < L_TOT; kb += 64) {
        const int kbn = (kb + 64 < L_TOT) ? (kb + 64) : kLo;
        stageV(kb);
        stageK(kbn, p ^ 1);
        asm volatile("s_waitcnt vmcnt(8)" ::: "memory");
        __builtin_amdgcn_s_barrier();
        __builtin_amdgcn_sched_barrier(0);

        const f16* kbase = &lds_k[p][0];
        floatx4 sacc[2][4] = {};
        __builtin_amdgcn_s_setprio(1);
#pragma unroll
        for (int kf = 0; kf < 4; ++kf) {
            int r = kf * 16 + rl;
#pragma unroll
            for (int kc = 0; kc < 4; ++kc) {
                half8 bk = *(const half8*)(kbase + r * 128 + (((kc * 4 + rq) ^ (r & 15)) * 8));
                sacc[0][kf] = __builtin_amdgcn_mfma_f32_16x16x32_f16(aq[0][kc], bk, sacc[0][kf], 0, 0, 0);
                sacc[1][kf] = __builtin_amdgcn_mfma_f32_16x16x32_f16(aq[1][kc], bk, sacc[1][kf], 0, 0, 0);
            }
        }
        __builtin_amdgcn_s_setprio(0);
        // static-max softmax: p = exp(s - 4)
#pragma unroll
        for (int qt = 0; qt < 2; ++qt)
#pragma unroll
            for (int kf = 0; kf < 4; ++kf)
#pragma unroll
                for (int j = 0; j < 4; ++j) {
                    float pv = __expf(sacc[qt][kf][j] - 4.0f);
                    p_lds[w][qt * 16 + rq * 4 + j][kf * 16 + rl] = (f16)pv;
                }

        asm volatile("s_waitcnt vmcnt(4)" ::: "memory");
        __builtin_amdgcn_s_barrier();
        __builtin_amdgcn_sched_barrier(0);

        __builtin_amdgcn_s_setprio(1);
#pragma unroll
        for (int kc = 0; kc < 2; ++kc) {
            half8 ap0 = *(const half8*)(&p_lds[w][0 * 16 + rl][kc * 32 + rq * 8]);
            half8 ap1 = *(const half8*)(&p_lds[w][1 * 16 + rl][kc * 32 + rq * 8]);
            accl[0] = __builtin_amdgcn_mfma_f32_16x16x32_f16(ap0, vone, accl[0], 0, 0, 0);
            accl[1] = __builtin_amdgcn_mfma_f32_16x16x32_f16(ap1, vone, accl[1], 0, 0, 0);
#pragma unroll
            for (int dt = 0; dt < 8; ++dt) {
                int d = dt * 16 + rl;
                int g10 = (d & 1) * 8 + kc * 4 + rq;
                half8 bv = *(const half8*)(lds_v + (d >> 1) * 128 + ((g10 ^ ((d >> 1) & 15)) * 8));
                acc[0][dt] = __builtin_amdgcn_mfma_f32_16x16x32_f16(ap0, bv, acc[0][dt], 0, 0, 0);
                acc[1][dt] = __builtin_amdgcn_mfma_f32_16x16x32_f16(ap1, bv, acc[1][dt], 0, 0, 0);
            }
        }
        __builtin_amdgcn_s_setprio(0);
        __builtin_amdgcn_s_barrier();
        p ^= 1;
    }

#pragma unroll
    for (int qt = 0; qt < 2; ++qt)
#pragma unroll
        for (int j = 0; j < 4; ++j) {
            float li = 1.0f / accl[qt][j];
            int row = q0 + qt * 16 + rq * 4 + j;
#pragma unroll
            for (int dt = 0; dt < 8; ++dt)
                xH[(size_t)row * DIM_C + h * HD + dt * 16 + rl] = (f16)(acc[qt][dt][j] * li);
        }
}

// ---------------------------------------------------------------- launch
extern "C" void kernel_launch(void* const* d_in, const int* in_sizes, int n_in,
                              void* d_out, int out_size, void* d_ws, size_t ws_size,
                              hipStream_t stream) {
    const float* noise = (const float*)d_in[0];
    const float* cond  = (const float*)d_in[1];
    const float* nrope = (const float*)d_in[2];
    const float* crope = (const float*)d_in[3];
    const float* Wq = (const float*)d_in[4];
    const float* Wk = (const float*)d_in[5];
    const float* Wv = (const float*)d_in[6];
    const float* Wo = (const float*)d_in[7];
    const float* bq = (const float*)d_in[8];
    const float* bk = (const float*)d_in[9];
    const float* bv = (const float*)d_in[10];
    const float* bo = (const float*)d_in[11];
    const float* qs = (const float*)d_in[12];
    const float* ks = (const float*)d_in[13];
    const float* vs = (const float*)d_in[14];
    const float* lqd = (const float*)d_in[15];
    const float* lqu = (const float*)d_in[16];
    const float* lkd = (const float*)d_in[17];
    const float* lku = (const float*)d_in[18];
    const float* lvd = (const float*)d_in[19];
    const float* lvu = (const float*)d_in[20];
    const float* lod = (const float*)d_in[21];
    const float* lou = (const float*)d_in[22];
    (void)in_sizes; (void)n_in; (void)out_size;

    char* ws = (char*)d_ws;
    const size_t SZ_LD = (size_t)L_TOT * DIM_C * sizeof(f16);   // 12.58 MB
    const size_t SZ_W  = (size_t)DIM_C * DIM_C * sizeof(f16);   //  8.39 MB
    size_t o = 0;
    auto take = [&](size_t b) { size_t r = o; o += (b + 255) & ~(size_t)255; return r; };
    f16* jointH = (f16*)(ws + take(SZ_LD));
    f16* WTqkv  = (f16*)(ws + take(4 * SZ_W));                  // Wq,Wk,Wv,Wo contiguous
    f16* WT3    = WTqkv + (size_t)3 * 2048 * 2048;
    f16* downT  = (f16*)(ws + take((size_t)4 * 128 * 2048 * 2));// lqd,lkd,lvd,lod
    f16* downTo = downT + (size_t)3 * 128 * 2048;
    f16* upT    = (f16*)(ws + take((size_t)4 * 2048 * 128 * 2));// lqu,lku,lvu,lou
    f16* upTo   = upT + (size_t)3 * 2048 * 128;
    f16* q16    = (f16*)(ws + take(3 * SZ_LD));                 // q,k,v contiguous
    f16* k16    = q16 + (size_t)L_TOT * DIM_C;
    f16* v16    = k16 + (size_t)L_TOT * DIM_C;
    f16* t_all  = (f16*)(ws + take((size_t)1024 * 384 * 2));
    f16* t_o    = (f16*)(ws + take((size_t)1024 * 128 * 2));
    f16* qHd    = (f16*)(ws + take(SZ_LD));
    f16* kHd    = (f16*)(ws + take(SZ_LD));
    f16* vTd    = (f16*)(ws + take(SZ_LD));
    f16* xH     = (f16*)(ws + take(SZ_LD));
    if (o > ws_size) {
        sentinel_kernel<<<1, 1, 0, stream>>>((float*)d_out);
        return;
    }

    // 1) fused cast + batched weight transposes
    cast_joint<<<dim3(6144), 256, 0, stream>>>(noise, cond, jointH);
    transpose_cast4<<<dim3(64, 64, 4), 256, 0, stream>>>(Wq, Wk, Wv, Wo, WTqkv, 2048, 2048,
                                                         (long long)2048 * 2048);
    transpose_cast4<<<dim3(4, 64, 4), 256, 0, stream>>>(lqd, lkd, lvd, lod, downT, 2048, 128,
                                                        (long long)128 * 2048);
    transpose_cast4<<<dim3(64, 4, 4), 256, 0, stream>>>(lqu, lku, lvu, lou, upT, 128, 2048,
                                                        (long long)2048 * 128);

    // 2) merged QKV projection, lora-down (stacked), merged lora-up (cond rows)
    gemm_tn<1, 0, 1, 1><<<dim3(48, 24), 256, 0, stream>>>(
        jointH, WTqkv, q16, bq, bk, bv, 3072, 6144, 2048, 2048, 2048, 2048, 1.0f);
    gemm_tn<1, 0, 0, 0><<<dim3(3, 8), 256, 0, stream>>>(jointH + (size_t)2048 * 2048, downT, t_all,
                                                        nullptr, nullptr, nullptr,
                                                        1024, 384, 2048, 2048, 2048, 384, 1.0f);
    gemm_tn<1, 1, 0, 2><<<dim3(48, 8), 256, 0, stream>>>(t_all, upT, q16 + (size_t)2048 * 2048,
                                                         nullptr, nullptr, nullptr,
                                                         1024, 6144, 128, 384, 128, 2048, 1.0f);

    // 3) fused RMS norm + RoPE + V transpose
    norm_rope_v<<<dim3(96, 16), 256, 0, stream>>>(q16, k16, v16, qs, ks, vs, nrope, crope,
                                                  qHd, kHd, vTd);

    // 4) flash attention -> xH [L][2048]
    flash_kernel<<<dim3(384), 256, 0, stream>>>(qHd, kHd, vTd, xH);

    // 5) output projection (+bias) and LoRA-o
    gemm_tn<0, 0, 1, 0><<<dim3(16, 24), 256, 0, stream>>>(xH, WT3, d_out, bo, nullptr, nullptr,
                                                          3072, 2048, 2048, 2048, 2048, 2048, 1.0f);
    gemm_tn<1, 0, 0, 0><<<dim3(1, 8), 256, 0, stream>>>(xH + (size_t)2048 * 2048, downTo, t_o,
                                                        nullptr, nullptr, nullptr,
                                                        1024, 128, 2048, 2048, 2048, 128, 1.0f);
    gemm_tn<0, 1, 0, 0><<<dim3(16, 8), 256, 0, stream>>>(t_o, upTo, (float*)d_out + (size_t)2048 * 2048,
                                                         nullptr, nullptr, nullptr,
                                                         1024, 2048, 128, 128, 128, 2048, 1.0f);
}

// Round 11
// 338.367 us; speedup vs baseline: 2.4175x; 1.0509x over previous
//
#include <hip/hip_runtime.h>

typedef _Float16 f16;
typedef _Float16 half8 __attribute__((ext_vector_type(8)));
typedef float floatx4 __attribute__((ext_vector_type(4)));

#define L_TOT   3072
#define L_NZ    2048
#define DIM_C   2048
#define NH      16
#define HD      128

// ---------------------------------------------------------------- helpers
__device__ __forceinline__ void gl_lds16(const f16* g, f16* l) {
    __builtin_amdgcn_global_load_lds((__attribute__((address_space(1))) void*)g,
                                     (__attribute__((address_space(3))) void*)l,
                                     16, 0, 0);
}

__global__ void sentinel_kernel(float* out) { out[0] = 1.0e6f; }

// ---------------------------------------------------------------- fused cast: joint = [noise;cond] f32 -> f16
__global__ __launch_bounds__(256)
void cast_joint(const float* __restrict__ noise, const float* __restrict__ cond,
                f16* __restrict__ out) {
    int i = (blockIdx.x * 256 + threadIdx.x) * 4;
    const float* src; int off;
    if (i < 2048 * 2048) { src = noise; off = i; }
    else                 { src = cond;  off = i - 2048 * 2048; }
    float4 v = *(const float4*)(src + off);
    out[i+0] = (f16)v.x; out[i+1] = (f16)v.y;
    out[i+2] = (f16)v.z; out[i+3] = (f16)v.w;
}

// ---------------------------------------------------------------- batched transpose(+cast): out[z][c][r] = in_z[r][c]
__global__ __launch_bounds__(256)
void transpose_cast4(const float* __restrict__ s0, const float* __restrict__ s1,
                     const float* __restrict__ s2, const float* __restrict__ s3,
                     f16* __restrict__ dstBase, int R, int C, long long outBatch) {
    const float* in = (blockIdx.z == 0) ? s0 : (blockIdx.z == 1) ? s1 : (blockIdx.z == 2) ? s2 : s3;
    f16* out = dstBase + (long long)blockIdx.z * outBatch;
    __shared__ f16 tile[32][33];
    int x = threadIdx.x & 31, y0 = threadIdx.x >> 5;
    int r0 = blockIdx.y * 32, c0 = blockIdx.x * 32;
#pragma unroll
    for (int i = 0; i < 4; ++i) {
        int y = y0 + i * 8;
        tile[y][x] = (f16)in[(size_t)(r0 + y) * C + (c0 + x)];
    }
    __syncthreads();
#pragma unroll
    for (int i = 0; i < 4; ++i) {
        int y = y0 + i * 8;
        out[(size_t)(c0 + y) * R + (r0 + x)] = tile[x][y];
    }
}

// ---------------------------------------------------------------- GEMM v2 (template): C = A * BT^T
// 128x128 tile, BK=64, XOR-swizzled LDS, double-buffered counted vmcnt(8).
// MODE 0: plain. MODE 2: lora-up merged (A += chunk*128, per-chunk C base).
template<int WRITE_HALF, int ACCUM, int ADD_BIAS, int MODE>
__global__ __launch_bounds__(256, 2)
void gemm_tn(const f16* __restrict__ A, const f16* __restrict__ BT,
             void* __restrict__ Cv,
             const float* __restrict__ bias0,
             int M, int N, int K, int lda, int ldb, int ldc) {
    __shared__ __align__(16) f16 lds[2][2][128 * 64];
    const int tid  = threadIdx.x;
    const int lane = tid & 63, wave = tid >> 6;
    const int m0 = blockIdx.y * 128, n0 = blockIdx.x * 128;
    const int wr = wave >> 1, wc = wave & 1;
    floatx4 acc[4][4] = {};

    if (MODE == 2) A += (size_t)(n0 >> 11) * 128;

    const int r0i = tid >> 3;
    const int gch = (tid & 7) ^ (r0i & 7);
    const f16* gA0 = A  + (size_t)(m0 + r0i) * lda + gch * 8;
    const f16* gB0 = BT + (size_t)(n0 + r0i) * ldb + gch * 8;
    const int ldsW = wave * 512;

    auto stage = [&](int buf, int k0) {
#pragma unroll
        for (int is = 0; is < 4; ++is)
            gl_lds16(gA0 + k0 + (size_t)is * 32 * lda, &lds[buf][0][0] + is * 2048 + ldsW);
#pragma unroll
        for (int is = 0; is < 4; ++is)
            gl_lds16(gB0 + k0 + (size_t)is * 32 * ldb, &lds[buf][1][0] + is * 2048 + ldsW);
    };

    const int rl = lane & 15, cq = lane >> 4;

    const int nIter = K >> 6;
    stage(0, 0);
    int cur = 0;
    for (int t = 0; t < nIter; ++t) {
        const int k0n = (t + 1 < nIter) ? (t + 1) * 64 : 0;
        stage(cur ^ 1, k0n);
        asm volatile("s_waitcnt vmcnt(8)" ::: "memory");
        __builtin_amdgcn_s_barrier();
        __builtin_amdgcn_sched_barrier(0);
#pragma unroll
        for (int kh = 0; kh < 2; ++kh) {
            half8 af[4], bf[4];
#pragma unroll
            for (int m = 0; m < 4; ++m) {
                int row = wr * 64 + m * 16 + rl;
                int pos = (kh * 4 + cq) ^ (row & 7);
                af[m] = *(const half8*)(&lds[cur][0][row * 64 + pos * 8]);
            }
#pragma unroll
            for (int n = 0; n < 4; ++n) {
                int row = wc * 64 + n * 16 + rl;
                int pos = (kh * 4 + cq) ^ (row & 7);
                bf[n] = *(const half8*)(&lds[cur][1][row * 64 + pos * 8]);
            }
#pragma unroll
            for (int m = 0; m < 4; ++m)
#pragma unroll
                for (int n = 0; n < 4; ++n)
                    acc[m][n] = __builtin_amdgcn_mfma_f32_16x16x32_f16(af[m], bf[n], acc[m][n], 0, 0, 0);
        }
        __builtin_amdgcn_s_barrier();
        __builtin_amdgcn_sched_barrier(0);
        cur ^= 1;
    }

    const int rq = lane >> 4;
    size_t cbase = 0;
    if (MODE == 2) cbase = (size_t)(n0 >> 11) * ((size_t)L_TOT * DIM_C);
#pragma unroll
    for (int m = 0; m < 4; ++m) {
        int row = m0 + wr * 64 + m * 16 + rq * 4;
#pragma unroll
        for (int n = 0; n < 4; ++n) {
            int col = n0 + wc * 64 + n * 16 + rl;
            int ccol = (MODE == 2) ? (col & 2047) : col;
            float badd = ADD_BIAS ? bias0[ccol] : 0.0f;
#pragma unroll
            for (int j = 0; j < 4; ++j) {
                float v = acc[m][n][j] + badd;
                size_t idx = cbase + (size_t)(row + j) * ldc + ccol;
                if (WRITE_HALF) {
                    f16* C = (f16*)Cv;
                    if (ACCUM) v += (float)C[idx];
                    C[idx] = (f16)v;
                } else {
                    float* C = (float*)Cv;
                    if (ACCUM) v += C[idx];
                    C[idx] = v;
                }
            }
        }
    }
}

// ---------------------------------------------------------------- dual-job GEMM (runtime params; hot loop identical)
// Job0 blocks [0,nb0): optional QKV-split (mode0=1). Job1 blocks [nb0,..): plain, no bias.
// All jobs: no accum, shared K.
__global__ __launch_bounds__(256, 2)
void gemm_pair(int nb0, int nbx0,
               const f16* __restrict__ A0, const f16* __restrict__ BT0, void* C0,
               const float* __restrict__ b00, const float* __restrict__ b01, const float* __restrict__ b02,
               int lda0, int ldb0, int ldc0, int wh0, int ab0, int mode0,
               int nbx1,
               const f16* __restrict__ A1, const f16* __restrict__ BT1, void* C1,
               int lda1, int ldb1, int ldc1, int wh1,
               int K) {
    __shared__ __align__(16) f16 lds[2][2][128 * 64];
    const int tid  = threadIdx.x;
    const int lane = tid & 63, wave = tid >> 6;
    const int bid = blockIdx.x;
    const bool j0 = (bid < nb0);
    const int lb  = j0 ? bid : (bid - nb0);
    const int nbx = j0 ? nbx0 : nbx1;
    const int bx = lb % nbx, by = lb / nbx;
    const int m0 = by * 128, n0 = bx * 128;
    const f16* A  = j0 ? A0  : A1;
    const f16* BT = j0 ? BT0 : BT1;
    const int lda = j0 ? lda0 : lda1, ldb = j0 ? ldb0 : ldb1, ldc = j0 ? ldc0 : ldc1;
    const int wr = wave >> 1, wc = wave & 1;
    floatx4 acc[4][4] = {};

    const int r0i = tid >> 3;
    const int gch = (tid & 7) ^ (r0i & 7);
    const f16* gA0 = A  + (size_t)(m0 + r0i) * lda + gch * 8;
    const f16* gB0 = BT + (size_t)(n0 + r0i) * ldb + gch * 8;
    const int ldsW = wave * 512;

    auto stage = [&](int buf, int k0) {
#pragma unroll
        for (int is = 0; is < 4; ++is)
            gl_lds16(gA0 + k0 + (size_t)is * 32 * lda, &lds[buf][0][0] + is * 2048 + ldsW);
#pragma unroll
        for (int is = 0; is < 4; ++is)
            gl_lds16(gB0 + k0 + (size_t)is * 32 * ldb, &lds[buf][1][0] + is * 2048 + ldsW);
    };

    const int rl = lane & 15, cq = lane >> 4;
    const int nIter = K >> 6;
    stage(0, 0);
    int cur = 0;
    for (int t = 0; t < nIter; ++t) {
        const int k0n = (t + 1 < nIter) ? (t + 1) * 64 : 0;
        stage(cur ^ 1, k0n);
        asm volatile("s_waitcnt vmcnt(8)" ::: "memory");
        __builtin_amdgcn_s_barrier();
        __builtin_amdgcn_sched_barrier(0);
#pragma unroll
        for (int kh = 0; kh < 2; ++kh) {
            half8 af[4], bf[4];
#pragma unroll
            for (int m = 0; m < 4; ++m) {
                int row = wr * 64 + m * 16 + rl;
                int pos = (kh * 4 + cq) ^ (row & 7);
                af[m] = *(const half8*)(&lds[cur][0][row * 64 + pos * 8]);
            }
#pragma unroll
            for (int n = 0; n < 4; ++n) {
                int row = wc * 64 + n * 16 + rl;
                int pos = (kh * 4 + cq) ^ (row & 7);
                bf[n] = *(const half8*)(&lds[cur][1][row * 64 + pos * 8]);
            }
#pragma unroll
            for (int m = 0; m < 4; ++m)
#pragma unroll
                for (int n = 0; n < 4; ++n)
                    acc[m][n] = __builtin_amdgcn_mfma_f32_16x16x32_f16(af[m], bf[n], acc[m][n], 0, 0, 0);
        }
        __builtin_amdgcn_s_barrier();
        __builtin_amdgcn_sched_barrier(0);
        cur ^= 1;
    }

    const int rq = lane >> 4;
    const int wh = j0 ? wh0 : wh1;
    const int ab = j0 ? ab0 : 0;
    const int md = j0 ? mode0 : 0;
    void* Cv = j0 ? C0 : C1;
    size_t cbase = 0;
    const float* bias = b00;
    if (md == 1) {
        int chunk = n0 >> 11;
        bias = (chunk == 0) ? b00 : ((chunk == 1) ? b01 : b02);
        cbase = (size_t)chunk * ((size_t)L_TOT * DIM_C);
    }
#pragma unroll
    for (int m = 0; m < 4; ++m) {
        int row = m0 + wr * 64 + m * 16 + rq * 4;
#pragma unroll
        for (int n = 0; n < 4; ++n) {
            int col = n0 + wc * 64 + n * 16 + rl;
            int ccol = (md == 1) ? (col & 2047) : col;
            float badd = ab ? bias[ccol] : 0.0f;
#pragma unroll
            for (int j = 0; j < 4; ++j) {
                float v = acc[m][n][j] + badd;
                size_t idx = cbase + (size_t)(row + j) * ldc + ccol;
                if (wh) ((f16*)Cv)[idx] = (f16)v;
                else    ((float*)Cv)[idx] = v;
            }
        }
    }
}

// ---------------------------------------------------------------- fused RMS norm + RoPE + V-transpose (unchanged)
__global__ __launch_bounds__(256)
void norm_rope_v(const f16* __restrict__ q16, const f16* __restrict__ k16, const f16* __restrict__ v16,
                 const float* __restrict__ qs, const float* __restrict__ ks, const float* __restrict__ vs,
                 const float* __restrict__ nrope, const float* __restrict__ crope,
                 f16* __restrict__ qH, f16* __restrict__ kH, f16* __restrict__ vT) {
    __shared__ f16 vtile[128][33];
    const int t = threadIdx.x, rloc = t >> 3, c = t & 7;
    const int r = blockIdx.x * 32 + rloc, h = blockIdx.y;
    const int d0 = c * 8;
    const size_t src = (size_t)r * DIM_C + h * HD;
    half8 qlv = *(const half8*)(q16 + src + d0);
    half8 qhv = *(const half8*)(q16 + src + 64 + d0);
    half8 klv = *(const half8*)(k16 + src + d0);
    half8 khv = *(const half8*)(k16 + src + 64 + d0);
    half8 vlv = *(const half8*)(v16 + src + d0);
    half8 vhv = *(const half8*)(v16 + src + 64 + d0);
    float ql[8], qh[8], kl[8], kh[8], vl[8], vh[8];
    float sq = 0.f, sk = 0.f, sv = 0.f;
#pragma unroll
    for (int i = 0; i < 8; ++i) {
        ql[i] = (float)qlv[i]; qh[i] = (float)qhv[i];
        kl[i] = (float)klv[i]; kh[i] = (float)khv[i];
        vl[i] = (float)vlv[i]; vh[i] = (float)vhv[i];
        sq += ql[i]*ql[i] + qh[i]*qh[i];
        sk += kl[i]*kl[i] + kh[i]*kh[i];
        sv += vl[i]*vl[i] + vh[i]*vh[i];
    }
    sq += __shfl_xor(sq, 1); sq += __shfl_xor(sq, 2); sq += __shfl_xor(sq, 4);
    sk += __shfl_xor(sk, 1); sk += __shfl_xor(sk, 2); sk += __shfl_xor(sk, 4);
    sv += __shfl_xor(sv, 1); sv += __shfl_xor(sv, 2); sv += __shfl_xor(sv, 4);
    const float rqs = rsqrtf(sq * (1.0f / 128.0f) + 1e-6f);
    const float rks = rsqrtf(sk * (1.0f / 128.0f) + 1e-6f);
    const float rvs = rsqrtf(sv * (1.0f / 128.0f) + 1e-6f);
    const float* rp = (r < L_NZ) ? (nrope + (size_t)r * HD) : (crope + (size_t)(r - L_NZ) * HD);
    half8 qo_l, qo_h, ko_l, ko_h;
#pragma unroll
    for (int i = 0; i < 8; ++i) {
        float fr = rp[d0 + i];
        float cs = cosf(fr), sn = sinf(fr);
        float qnl = ql[i] * rqs * qs[d0 + i],      qnh = qh[i] * rqs * qs[64 + d0 + i];
        float knl = kl[i] * rks * ks[d0 + i],      knh = kh[i] * rks * ks[64 + d0 + i];
        qo_l[i] = (f16)((qnl * cs - qnh * sn) * 0.08838834764831845f);
        qo_h[i] = (f16)((qnh * cs + qnl * sn) * 0.08838834764831845f);
        ko_l[i] = (f16)(knl * cs - knh * sn);
        ko_h[i] = (f16)(knh * cs + knl * sn);
        vtile[d0 + i][rloc]      = (f16)(vl[i] * rvs * vs[d0 + i]);
        vtile[64 + d0 + i][rloc] = (f16)(vh[i] * rvs * vs[64 + d0 + i]);
    }
    const size_t dst = ((size_t)h * L_TOT + r) * HD;
    *(half8*)(qH + dst + d0) = qo_l;      *(half8*)(qH + dst + 64 + d0) = qo_h;
    *(half8*)(kH + dst + d0) = ko_l;      *(half8*)(kH + dst + 64 + d0) = ko_h;
    __syncthreads();
    const int dd = t >> 1, seg = (t & 1) * 16;
    half8 o0, o1;
#pragma unroll
    for (int i = 0; i < 8; ++i) { o0[i] = vtile[dd][seg + i]; o1[i] = vtile[dd][seg + 8 + i]; }
    f16* vdst = vT + ((size_t)h * HD + dd) * L_TOT + blockIdx.x * 32 + seg;
    *(half8*)(vdst)     = o0;
    *(half8*)(vdst + 8) = o1;
}

// ---------------------------------------------------------------- flash attention v5: QBLK=64, 768 blocks
// wave = 16 q-rows. 1D grid 768, XCD-clustered (xcd=bid&7 owns heads {xcd,xcd+8}); per XCD
// the 32 SHORT cond blocks (16 iters) dispatch first, then 64 long noise blocks (48 iters).
// K dbuf + counted vmcnt pipeline and static-max softmax unchanged from v4.
__global__ __launch_bounds__(256, 2)
void flash_kernel(const f16* __restrict__ qH, const f16* __restrict__ kH,
                  const f16* __restrict__ vT, f16* __restrict__ xH) {
    __shared__ __align__(16) f16 lds_k[2][64 * 128];
    __shared__ __align__(16) f16 lds_v[64 * 128];
    __shared__ __align__(16) f16 p_lds[4][16][72];
    const int tid = threadIdx.x;
    const int lane = tid & 63, w = tid >> 6;
    const int bid = blockIdx.x;
    const int xcd = bid & 7, rr = bid >> 3;     // rr in [0,96)
    int h, qb;
    if (rr < 32) { h = xcd + 8 * (rr >> 4); qb = 32 + (rr & 15); }     // cond shorts first
    else         { int li = rr - 32; h = xcd + 8 * (li >> 5); qb = li & 31; }  // noise longs
    const int q0 = qb * 64 + w * 16;
    const int rl = lane & 15, rq = lane >> 4;

    half8 aq[4];
    const f16* qbase = qH + ((size_t)h * L_TOT + q0) * HD;
#pragma unroll
    for (int kc = 0; kc < 4; ++kc)
        aq[kc] = *(const half8*)(qbase + (size_t)rl * HD + kc * 32 + rq * 8);

    floatx4 acc[8] = {};
    floatx4 accl = {};
    const half8 vone = {(f16)1.f, (f16)1.f, (f16)1.f, (f16)1.f,
                        (f16)1.f, (f16)1.f, (f16)1.f, (f16)1.f};

    const int kLo = (qb >= 32) ? L_NZ : 0;
    const f16* khead = kH + (size_t)h * L_TOT * HD;
    const f16* vhead = vT + (size_t)h * HD * L_TOT;

    auto stageK = [&](int kb, int pb) {
#pragma unroll
        for (int is = 0; is < 4; ++is) {
            int i = is * 256 + tid;
            int r = i >> 4, c = i & 15;
            gl_lds16(khead + (size_t)(kb + r) * HD + ((c ^ (r & 15)) * 8),
                     &lds_k[pb][0] + (is * 256 + w * 64) * 8);
        }
    };
    auto stageV = [&](int kb) {
#pragma unroll
        for (int is = 0; is < 4; ++is) {
            int i = is * 256 + tid;
            int pair = i >> 4, c10 = i & 15;
            int g10 = c10 ^ (pair & 15);
            int d = pair * 2 + (g10 >> 3), kchunk = g10 & 7;
            gl_lds16(vhead + (size_t)d * L_TOT + kb + kchunk * 8,
                     lds_v + (is * 256 + w * 64) * 8);
        }
    };

    asm volatile("s_waitcnt vmcnt(0)" ::: "memory");
    stageK(kLo, 0);
    int p = 0;
    for (int kb = kLo; kb < L_TOT; kb += 64) {
        const int kbn = (kb + 64 < L_TOT) ? (kb + 64) : kLo;
        stageV(kb);
        stageK(kbn, p ^ 1);
        asm volatile("s_waitcnt vmcnt(8)" ::: "memory");
        __builtin_amdgcn_s_barrier();
        __builtin_amdgcn_sched_barrier(0);

        const f16* kbase = &lds_k[p][0];
        floatx4 sacc[4] = {};
        __builtin_amdgcn_s_setprio(1);
#pragma unroll
        for (int kf = 0; kf < 4; ++kf) {
            int r = kf * 16 + rl;
#pragma unroll
            for (int kc = 0; kc < 4; ++kc) {
                half8 bk = *(const half8*)(kbase + r * 128 + (((kc * 4 + rq) ^ (r & 15)) * 8));
                sacc[kf] = __builtin_amdgcn_mfma_f32_16x16x32_f16(aq[kc], bk, sacc[kf], 0, 0, 0);
            }
        }
        __builtin_amdgcn_s_setprio(0);
#pragma unroll
        for (int kf = 0; kf < 4; ++kf)
#pragma unroll
            for (int j = 0; j < 4; ++j) {
                float pv = __expf(sacc[kf][j] - 4.0f);
                p_lds[w][rq * 4 + j][kf * 16 + rl] = (f16)pv;
            }

        asm volatile("s_waitcnt vmcnt(4)" ::: "memory");
        __builtin_amdgcn_s_barrier();
        __builtin_amdgcn_sched_barrier(0);

        __builtin_amdgcn_s_setprio(1);
#pragma unroll
        for (int kc = 0; kc < 2; ++kc) {
            half8 ap = *(const half8*)(&p_lds[w][rl][kc * 32 + rq * 8]);
            accl = __builtin_amdgcn_mfma_f32_16x16x32_f16(ap, vone, accl, 0, 0, 0);
#pragma unroll
            for (int dt = 0; dt < 8; ++dt) {
                int d = dt * 16 + rl;
                int g10 = (d & 1) * 8 + kc * 4 + rq;
                half8 bv = *(const half8*)(lds_v + (d >> 1) * 128 + ((g10 ^ ((d >> 1) & 15)) * 8));
                acc[dt] = __builtin_amdgcn_mfma_f32_16x16x32_f16(ap, bv, acc[dt], 0, 0, 0);
            }
        }
        __builtin_amdgcn_s_setprio(0);
        __builtin_amdgcn_s_barrier();
        p ^= 1;
    }

#pragma unroll
    for (int j = 0; j < 4; ++j) {
        float li = 1.0f / accl[j];
        int row = q0 + rq * 4 + j;
#pragma unroll
        for (int dt = 0; dt < 8; ++dt)
            xH[(size_t)row * DIM_C + h * HD + dt * 16 + rl] = (f16)(acc[dt][j] * li);
    }
}

// ---------------------------------------------------------------- launch
extern "C" void kernel_launch(void* const* d_in, const int* in_sizes, int n_in,
                              void* d_out, int out_size, void* d_ws, size_t ws_size,
                              hipStream_t stream) {
    const float* noise = (const float*)d_in[0];
    const float* cond  = (const float*)d_in[1];
    const float* nrope = (const float*)d_in[2];
    const float* crope = (const float*)d_in[3];
    const float* Wq = (const float*)d_in[4];
    const float* Wk = (const float*)d_in[5];
    const float* Wv = (const float*)d_in[6];
    const float* Wo = (const float*)d_in[7];
    const float* bq = (const float*)d_in[8];
    const float* bk = (const float*)d_in[9];
    const float* bv = (const float*)d_in[10];
    const float* bo = (const float*)d_in[11];
    const float* qs = (const float*)d_in[12];
    const float* ks = (const float*)d_in[13];
    const float* vs = (const float*)d_in[14];
    const float* lqd = (const float*)d_in[15];
    const float* lqu = (const float*)d_in[16];
    const float* lkd = (const float*)d_in[17];
    const float* lku = (const float*)d_in[18];
    const float* lvd = (const float*)d_in[19];
    const float* lvu = (const float*)d_in[20];
    const float* lod = (const float*)d_in[21];
    const float* lou = (const float*)d_in[22];
    (void)in_sizes; (void)n_in; (void)out_size;

    char* ws = (char*)d_ws;
    const size_t SZ_LD = (size_t)L_TOT * DIM_C * sizeof(f16);
    const size_t SZ_W  = (size_t)DIM_C * DIM_C * sizeof(f16);
    size_t o = 0;
    auto take = [&](size_t b) { size_t r = o; o += (b + 255) & ~(size_t)255; return r; };
    f16* jointH = (f16*)(ws + take(SZ_LD));
    f16* WTqkv  = (f16*)(ws + take(4 * SZ_W));                  // Wq,Wk,Wv,Wo contiguous
    f16* WT3    = WTqkv + (size_t)3 * 2048 * 2048;
    f16* downT  = (f16*)(ws + take((size_t)4 * 128 * 2048 * 2));// lqd,lkd,lvd,lod
    f16* downTo = downT + (size_t)3 * 128 * 2048;
    f16* upT    = (f16*)(ws + take((size_t)4 * 2048 * 128 * 2));// lqu,lku,lvu,lou
    f16* upTo   = upT + (size_t)3 * 2048 * 128;
    f16* q16    = (f16*)(ws + take(3 * SZ_LD));                 // q,k,v contiguous
    f16* k16    = q16 + (size_t)L_TOT * DIM_C;
    f16* v16    = k16 + (size_t)L_TOT * DIM_C;
    f16* t_all  = (f16*)(ws + take((size_t)1024 * 384 * 2));
    f16* t_o    = (f16*)(ws + take((size_t)1024 * 128 * 2));
    f16* qHd    = (f16*)(ws + take(SZ_LD));
    f16* kHd    = (f16*)(ws + take(SZ_LD));
    f16* vTd    = (f16*)(ws + take(SZ_LD));
    f16* xH     = (f16*)(ws + take(SZ_LD));
    if (o > ws_size) {
        sentinel_kernel<<<1, 1, 0, stream>>>((float*)d_out);
        return;
    }

    // 1) fused cast + batched weight transposes
    cast_joint<<<dim3(6144), 256, 0, stream>>>(noise, cond, jointH);
    transpose_cast4<<<dim3(64, 64, 4), 256, 0, stream>>>(Wq, Wk, Wv, Wo, WTqkv, 2048, 2048,
                                                         (long long)2048 * 2048);
    transpose_cast4<<<dim3(4, 64, 4), 256, 0, stream>>>(lqd, lkd, lvd, lod, downT, 2048, 128,
                                                        (long long)128 * 2048);
    transpose_cast4<<<dim3(64, 4, 4), 256, 0, stream>>>(lqu, lku, lvu, lou, upT, 128, 2048,
                                                        (long long)2048 * 128);

    // 2) merged {QKV projection + lora-down} one dispatch; merged lora-up
    gemm_pair<<<dim3(1152 + 24), 256, 0, stream>>>(
        1152, 48, jointH, WTqkv, q16, bq, bk, bv, 2048, 2048, 2048, /*wh*/1, /*ab*/1, /*mode*/1,
        3, jointH + (size_t)2048 * 2048, downT, t_all, 2048, 2048, 384, /*wh*/1,
        2048);
    gemm_tn<1, 1, 0, 2><<<dim3(48, 8), 256, 0, stream>>>(t_all, upT, q16 + (size_t)2048 * 2048,
                                                         nullptr, 1024, 6144, 128, 384, 128, 2048);

    // 3) fused RMS norm + RoPE + V transpose
    norm_rope_v<<<dim3(96, 16), 256, 0, stream>>>(q16, k16, v16, qs, ks, vs, nrope, crope,
                                                  qHd, kHd, vTd);

    // 4) flash attention -> xH [L][2048]
    flash_kernel<<<dim3(768), 256, 0, stream>>>(qHd, kHd, vTd, xH);

    // 5) merged {output projection + lora-o-down}; lora-o-up accumulates into f32 out
    gemm_pair<<<dim3(384 + 8), 256, 0, stream>>>(
        384, 16, xH, WT3, d_out, bo, nullptr, nullptr, 2048, 2048, 2048, /*wh*/0, /*ab*/1, /*mode*/0,
        1, xH + (size_t)2048 * 2048, downTo, t_o, 2048, 2048, 128, /*wh*/1,
        2048);
    gemm_tn<0, 1, 0, 0><<<dim3(16, 8), 256, 0, stream>>>(t_o, upTo, (float*)d_out + (size_t)2048 * 2048,
                                                         nullptr, 1024, 2048, 128, 128, 128, 2048);
}